// Round 10
// baseline (366.969 us; speedup 1.0000x reference)
//
#include <hip/hip_runtime.h>
#include <hip/hip_bf16.h>
#include <math.h>

#define N_NODES 100000
#define N_EDGES 1600000
#define N_GRAPHS 64
#define EPS 1e-5f
#define NBUCK 391       // ceil(N_NODES / 256)
#define EBLK 782        // ceil(N_EDGES / 2048)  (setup bhist blocks)
#define BSCAT_GRID 196  // ceil(N_EDGES / 8192)
#define SEG_NBLK 3125   // 3125 * 32 = 100000 node slots (exact)
#define GEMM_TILES 1563 // ceil(N_NODES / 64)

typedef unsigned int u32;
typedef __attribute__((ext_vector_type(8))) short short8;
typedef __attribute__((ext_vector_type(4))) float f32x4;

static __device__ __forceinline__ ushort f2bf(float f) {
  u32 x = __float_as_uint(f);
  u32 r = (x + 0x7fffu + ((x >> 16) & 1u)) >> 16;  // RNE; inputs finite
  return (ushort)r;
}
static __device__ __forceinline__ float bflo(u32 w) { return __uint_as_float(w << 16); }
static __device__ __forceinline__ float bfhi(u32 w) { return __uint_as_float(w & 0xffff0000u); }
static __device__ __forceinline__ void decode8(uint4 w, float* f) {
  f[0] = bflo(w.x); f[1] = bfhi(w.x); f[2] = bflo(w.y); f[3] = bfhi(w.y);
  f[4] = bflo(w.z); f[5] = bfhi(w.z); f[6] = bflo(w.w); f[7] = bfhi(w.w);
}

// ---------- setup: bhist + weight pack + graph bounds + zero accumulators ----------
// Wb[layer][kh(2)][ct(8)][lane(64)] = uint4 (8 bf16): lane l, elem j ->
//   Wc[kh*32 + (l>>4)*8 + j][ct*16 + (l&15)], Wc = [A-B | B] (64 x 128)
__global__ __launch_bounds__(256) void setup_k(
    const int* __restrict__ dst, u32* __restrict__ bcnt,
    const float* __restrict__ W1, const float* __restrict__ W2,
    const float* __restrict__ W3, uint4* __restrict__ Wb,
    const int* __restrict__ batch, u32* __restrict__ bounds,
    u32* __restrict__ zbase) {
  __shared__ u32 csh[NBUCK];
  int bid = blockIdx.x, t = threadIdx.x;
  if (bid < EBLK) {
    for (int i = t; i < NBUCK; i += 256) csh[i] = 0;
    __syncthreads();
    int base = bid * 2048;
#pragma unroll
    for (int k = 0; k < 8; ++k) {
      int e = base + k * 256 + t;
      if (e < N_EDGES) atomicAdd(&csh[(u32)dst[e] >> 8], 1u);
    }
    __syncthreads();
    for (int i = t; i < NBUCK; i += 256) {
      u32 cc = csh[i];
      if (cc) atomicAdd(&bcnt[i], cc);
    }
  } else if (bid < EBLK + 12) {
    int g = (bid - EBLK) * 256 + t;
    if (g >= 3072) return;
    int layer = g >> 10, rem = g & 1023;
    int kh = rem >> 9, ct = (rem >> 6) & 7, l = rem & 63;
    const float* W = (layer == 0) ? W1 : (layer == 1) ? W2 : W3;
    int c = ct * 16 + (l & 15);
    u32 w[4];
#pragma unroll
    for (int jj = 0; jj < 4; ++jj) {
      int k0 = kh * 32 + (l >> 4) * 8 + 2 * jj;
      float v0, v1;
      if (c < 64) {
        v0 = W[k0 * 64 + c] - W[(64 + k0) * 64 + c];
        v1 = W[(k0 + 1) * 64 + c] - W[(65 + k0) * 64 + c];
      } else {
        v0 = W[(64 + k0) * 64 + (c - 64)];
        v1 = W[(65 + k0) * 64 + (c - 64)];
      }
      w[jj] = (u32)f2bf(v0) | ((u32)f2bf(v1) << 16);
    }
    Wb[g] = make_uint4(w[0], w[1], w[2], w[3]);
  } else if (bid == EBLK + 12) {
    if (t > 64) return;
    int lo = 0, hi = N_NODES;
    while (lo < hi) {
      int mid = (lo + hi) >> 1;
      if (batch[mid] < t) lo = mid + 1; else hi = mid;
    }
    bounds[t] = (u32)lo;
  } else {
    // zero sums (4096) + bnacc (12288) + counter region (64)
    for (int i = t; i < 16448; i += 256) zbase[i] = 0u;
  }
}

// ---------- bucket scan -> boffs (exclusive, +total), bcur ----------
__global__ void bscan_k(const u32* __restrict__ bcnt, u32* __restrict__ boffs,
                        u32* __restrict__ bcur) {
  __shared__ u32 s[512];
  int t = threadIdx.x;
  u32 v = (t < NBUCK) ? bcnt[t] : 0u;
  s[t] = v;
  __syncthreads();
  for (int d = 1; d < 512; d <<= 1) {
    u32 a = (t >= d) ? s[t - d] : 0u;
    __syncthreads();
    s[t] += a;
    __syncthreads();
  }
  if (t < NBUCK) { boffs[t] = s[t] - v; bcur[t] = s[t] - v; }
  if (t == NBUCK - 1) boffs[NBUCK] = s[t];
}

// ---------- pass C: edges -> bucket-grouped packed pairs ((dst&255)<<24 | src) ----------
// 8192 edges/block (32/thread in registers) for write-combining on bucket fronts.
__global__ __launch_bounds__(256) void bscat_k(const int* __restrict__ src,
                                               const int* __restrict__ dst,
                                               u32* __restrict__ gcur,
                                               u32* __restrict__ pairs) {
  __shared__ u32 cnt[NBUCK];
  __shared__ u32 base[NBUCK];
  int t = threadIdx.x;
  for (int i = t; i < NBUCK; i += 256) cnt[i] = 0;
  __syncthreads();
  u32 pk[32], bk[32];
  int be = blockIdx.x * 8192;
#pragma unroll
  for (int k = 0; k < 32; ++k) {
    int e = be + k * 256 + t;
    if (e < N_EDGES) {
      u32 d = (u32)dst[e], s = (u32)src[e];
      u32 b = d >> 8;
      pk[k] = ((d & 255u) << 24) | s;
      bk[k] = b;
      atomicAdd(&cnt[b], 1u);
    } else bk[k] = 0xFFFFFFFFu;
  }
  __syncthreads();
  for (int i = t; i < NBUCK; i += 256) {
    u32 c = cnt[i];
    base[i] = c ? atomicAdd(&gcur[i], c) : 0u;
    cnt[i] = 0;
  }
  __syncthreads();
#pragma unroll
  for (int k = 0; k < 32; ++k) {
    if (bk[k] != 0xFFFFFFFFu) {
      u32 p = base[bk[k]] + atomicAdd(&cnt[bk[k]], 1u);
      pairs[p] = pk[k];
    }
  }
}

// ---------- fscat2 body: per-bucket node CSR (LDS hist+scan) + place ----------
static __device__ __forceinline__ void fscat2_body(
    int b, u32* SH, const u32* __restrict__ boffs, const u32* __restrict__ pairs,
    u32* __restrict__ esrc, u32* __restrict__ offs_g, u32* __restrict__ cnt_g) {
  u32* lcnt = SH; u32* lexc = SH + 256; u32* lcur = SH + 512;
  int t = threadIdx.x;
  u32 s0 = boffs[b], e0 = boffs[b + 1];
  lcnt[t] = 0;
  __syncthreads();
  for (u32 p = s0 + t; p < e0; p += 256) atomicAdd(&lcnt[pairs[p] >> 24], 1u);
  __syncthreads();
  u32 v = lcnt[t];
  lexc[t] = v;
  __syncthreads();
  for (int d = 1; d < 256; d <<= 1) {
    u32 a = (t >= d) ? lexc[t - d] : 0u;
    __syncthreads();
    lexc[t] += a;
    __syncthreads();
  }
  u32 excl = lexc[t] - v;
  int node = (b << 8) + t;
  if (node < N_NODES) { offs_g[node] = s0 + excl; cnt_g[node] = v; }
  lcur[t] = 0;
  lexc[t] = excl;
  __syncthreads();
  for (u32 p = s0 + t; p < e0; p += 256) {
    u32 pk = pairs[p];
    u32 dl = pk >> 24;
    u32 l = atomicAdd(&lcur[dl], 1u);
    esrc[s0 + lexc[dl] + l] = pk & 0x00FFFFFFu;
  }
}

// ---------- MFMA GEMM body: [u | v] = act(X) @ [A-B | B], u/v bf16 out ----------
// One 64-row tile; 4 waves; Xl XOR-swizzled (byte^=(row&7)<<4).
static __device__ __forceinline__ void gemm_body(
    int tile, u32* Xl,
    const void* __restrict__ xin, int xbf16, const uint4* __restrict__ Wb,
    const float* ab, const float* __restrict__ bias,
    ushort* __restrict__ ub, ushort* __restrict__ vb) {
  int t = threadIdx.x;
  int l = t & 63, wv = t >> 6;
  short8 bs[2][8];
#pragma unroll
  for (int kh = 0; kh < 2; ++kh)
#pragma unroll
    for (int ct = 0; ct < 8; ++ct) {
      uint4 tmp = Wb[(kh * 8 + ct) * 64 + l];
      __builtin_memcpy(&bs[kh][ct], &tmp, 16);
    }
  int srow = t >> 2, scol = (t & 3) * 16;
  int rb = tile * 64;
  int gr = rb + srow;
  u32 xb[8];
  if (gr < N_NODES) {
    if (xbf16) {
      const uint4* xp = (const uint4*)((const ushort*)xin + (size_t)gr * 64 + scol);
      uint4 p0 = xp[0], p1 = xp[1];
      u32 raw[8] = {p0.x, p0.y, p0.z, p0.w, p1.x, p1.y, p1.z, p1.w};
#pragma unroll
      for (int q = 0; q < 8; ++q) {
        int c = scol + 2 * q;
        float lo = fmaxf(fmaf(bflo(raw[q]), ab[c], ab[64 + c]), 0.f);
        float hi = fmaxf(fmaf(bfhi(raw[q]), ab[c + 1], ab[64 + c + 1]), 0.f);
        xb[q] = (u32)f2bf(lo) | ((u32)f2bf(hi) << 16);
      }
    } else {
      const float4* xp = (const float4*)((const float*)xin + (size_t)gr * 64 + scol);
#pragma unroll
      for (int q = 0; q < 4; ++q) {
        float4 a = xp[q];
        xb[2 * q]     = (u32)f2bf(a.x) | ((u32)f2bf(a.y) << 16);
        xb[2 * q + 1] = (u32)f2bf(a.z) | ((u32)f2bf(a.w) << 16);
      }
    }
  } else {
#pragma unroll
    for (int q = 0; q < 8; ++q) xb[q] = 0u;
  }
  int byte0 = srow * 128 + ((scol * 2) ^ ((srow & 7) << 4));
  int byte1 = srow * 128 + ((scol * 2 + 16) ^ ((srow & 7) << 4));
  *(uint4*)((char*)Xl + byte0) = make_uint4(xb[0], xb[1], xb[2], xb[3]);
  *(uint4*)((char*)Xl + byte1) = make_uint4(xb[4], xb[5], xb[6], xb[7]);
  __syncthreads();
  f32x4 acc[8];
#pragma unroll
  for (int ct = 0; ct < 8; ++ct) {
    float b0 = (ct < 4) ? bias[ct * 16 + (l & 15)] : 0.f;
    acc[ct] = (f32x4){b0, b0, b0, b0};
  }
  int arow = wv * 16 + (l & 15);
#pragma unroll
  for (int kh = 0; kh < 2; ++kh) {
    int abyte = arow * 128 + ((kh * 64 + ((l >> 4) * 16)) ^ ((arow & 7) << 4));
    short8 af = *(const short8*)((const char*)Xl + abyte);
#pragma unroll
    for (int ct = 0; ct < 8; ++ct)
      acc[ct] = __builtin_amdgcn_mfma_f32_16x16x32_bf16(af, bs[kh][ct], acc[ct], 0, 0, 0);
  }
  // C layout: col = l&15, row = 4*(l>>4)+reg (m89-verified)
  int rloc = rb + wv * 16 + 4 * (l >> 4);
#pragma unroll
  for (int ct = 0; ct < 4; ++ct) {
    int col = ct * 16 + (l & 15);
#pragma unroll
    for (int r = 0; r < 4; ++r) {
      int row = rloc + r;
      if (row < N_NODES) ub[(size_t)row * 64 + col] = f2bf(acc[ct][r]);
    }
  }
#pragma unroll
  for (int ct = 4; ct < 8; ++ct) {
    int col = ct * 16 + (l & 15) - 64;
#pragma unroll
    for (int r = 0; r < 4; ++r) {
      int row = rloc + r;
      if (row < N_NODES) vb[(size_t)row * 64 + col] = f2bf(acc[ct][r]);
    }
  }
}

// ---------- fused: fscat2 (391 blocks) || layer-1 GEMM (1563 blocks) ----------
__global__ __launch_bounds__(256) void fused_fg_k(
    const u32* __restrict__ boffs, const u32* __restrict__ pairs,
    u32* __restrict__ esrc, u32* __restrict__ offs_g, u32* __restrict__ cnt_g,
    const float* __restrict__ x, const uint4* __restrict__ Wb,
    const float* __restrict__ bias, ushort* __restrict__ ub, ushort* __restrict__ vb) {
  __shared__ u32 SH[2048];  // 8KB
  int bid = blockIdx.x;
  if (bid < NBUCK) fscat2_body(bid, SH, boffs, pairs, esrc, offs_g, cnt_g);
  else gemm_body(bid - NBUCK, SH, x, 0, Wb, nullptr, bias, ub, vb);
}

// ---------- standalone GEMM (layers 2,3): BN affine computed from bnacc slices ----------
__global__ __launch_bounds__(256) void gemm_k(
    const ushort* __restrict__ xin, const uint4* __restrict__ Wb,
    const float* __restrict__ bnacc, const float* __restrict__ g,
    const float* __restrict__ be, const float* __restrict__ bias,
    ushort* __restrict__ ub, ushort* __restrict__ vb) {
  __shared__ u32 Xl[2048];
  __shared__ float ab_sh[128];
  int t = threadIdx.x;
  if (t < 64) {
    float s1 = 0.f, s2 = 0.f;
    for (int s = 0; s < 32; ++s) {
      s1 += bnacc[s * 128 + t];
      s2 += bnacc[s * 128 + 64 + t];
    }
    float mu = s1 / (float)N_NODES;
    float var = s2 / (float)N_NODES - mu * mu;
    float al = g[t] / sqrtf(var + EPS);
    ab_sh[t] = al;
    ab_sh[64 + t] = be[t] - mu * al;
  }
  __syncthreads();
  gemm_body(blockIdx.x, Xl, xin, 1, Wb, ab_sh, bias, ub, vb);
}

// ---------- segmax: 1 node/slot, 8 lanes/node, uint4 gathers, unroll-4 ----------
// h = relu(u + max) bf16; BN partials -> sliced global accumulators (float atomics)
__global__ __launch_bounds__(256) void segmax_k(
    const ushort* __restrict__ v, const u32* __restrict__ offs,
    const u32* __restrict__ cnt, const u32* __restrict__ esrc,
    const ushort* __restrict__ ub, ushort* __restrict__ hb,
    float* __restrict__ bnacc) {
  int t = threadIdx.x;
  int lane = t & 63;
  int op = lane & 7;        // uint4 index within row (8 channels)
  int sub = lane >> 3;      // node sub-group within wave
  int wv = t >> 6;
  int node = blockIdx.x * 32 + wv * 8 + sub;   // grid*32 == N_NODES exactly
  const uint4* v4 = (const uint4*)v;
  const uint4* u4 = (const uint4*)ub;
  uint4* h4 = (uint4*)hb;
  u32 off = offs[node], deg = cnt[node];
  const u32* ep = esrc + off;
  float m[8];
#pragma unroll
  for (int j = 0; j < 8; ++j) m[j] = -INFINITY;
  u32 i = 0;
  for (; i + 4 <= deg; i += 4) {
    u32 sA = ep[i], sB = ep[i + 1], sC = ep[i + 2], sD = ep[i + 3];
    uint4 wA = v4[(size_t)sA * 8 + op];
    uint4 wB = v4[(size_t)sB * 8 + op];
    uint4 wC = v4[(size_t)sC * 8 + op];
    uint4 wD = v4[(size_t)sD * 8 + op];
    float fA[8], fB[8], fC[8], fD[8];
    decode8(wA, fA); decode8(wB, fB); decode8(wC, fC); decode8(wD, fD);
#pragma unroll
    for (int j = 0; j < 8; ++j)
      m[j] = fmaxf(fmaxf(m[j], fmaxf(fA[j], fB[j])), fmaxf(fC[j], fD[j]));
  }
  for (; i < deg; ++i) {
    uint4 w = v4[(size_t)ep[i] * 8 + op];
    float f[8]; decode8(w, f);
#pragma unroll
    for (int j = 0; j < 8; ++j) m[j] = fmaxf(m[j], f[j]);
  }
  uint4 uu = u4[(size_t)node * 8 + op];
  float uf[8]; decode8(uu, uf);
  float h[8];
#pragma unroll
  for (int j = 0; j < 8; ++j) h[j] = fmaxf(uf[j] + m[j], 0.f);  // relu(-inf)=0
  uint4 hw;
  hw.x = (u32)f2bf(h[0]) | ((u32)f2bf(h[1]) << 16);
  hw.y = (u32)f2bf(h[2]) | ((u32)f2bf(h[3]) << 16);
  hw.z = (u32)f2bf(h[4]) | ((u32)f2bf(h[5]) << 16);
  hw.w = (u32)f2bf(h[6]) | ((u32)f2bf(h[7]) << 16);
  h4[(size_t)node * 8 + op] = hw;
  // BN partials: channel c = op*8 + j; reduce 32 nodes per block
  __shared__ float red[2048];
#pragma unroll
  for (int j = 0; j < 8; ++j) red[t * 8 + j] = h[j];
  __syncthreads();
  float o1 = 0.f, o2 = 0.f;
  if (t < 64) {
    int cop = t >> 3, cj = t & 7;
    for (int q = 0; q < 32; ++q) o1 += red[(q * 8 + cop) * 8 + cj];
  }
  __syncthreads();
#pragma unroll
  for (int j = 0; j < 8; ++j) red[t * 8 + j] = h[j] * h[j];
  __syncthreads();
  if (t < 64) {
    int cop = t >> 3, cj = t & 7;
    for (int q = 0; q < 32; ++q) o2 += red[(q * 8 + cop) * 8 + cj];
    int slice = blockIdx.x & 31;
    atomicAdd(&bnacc[slice * 128 + t], o1);
    atomicAdd(&bnacc[slice * 128 + 64 + t], o2);
  }
}

// ---------- pool partials (uint4, high-MLP) + (last block) BN3 + head + softmax ----------
__global__ __launch_bounds__(256) void pool_head_k(
    const ushort* __restrict__ h3, const u32* __restrict__ bounds,
    float* __restrict__ sums, const float* __restrict__ bnacc3,
    const float* __restrict__ g3, const float* __restrict__ be3,
    const float* __restrict__ Wo, const float* __restrict__ bo,
    u32* __restrict__ counter, float* __restrict__ out) {
  int g = blockIdx.y;
  u32 s = bounds[g], e = bounds[g + 1];
  int t = threadIdx.x;
  int op = t & 7;                       // uint4 index (8 channels)
  int slot = blockIdx.x * 32 + (t >> 3);
  int nsl = gridDim.x * 32;             // 1024 node slots per graph
  const uint4* h4 = (const uint4*)h3;
  float acc[8];
#pragma unroll
  for (int j = 0; j < 8; ++j) acc[j] = 0.f;
  for (u32 n = s + slot; n < e; n += nsl) {
    uint4 w = h4[(size_t)n * 8 + op];
    float f[8]; decode8(w, f);
#pragma unroll
    for (int j = 0; j < 8; ++j) acc[j] += f[j];
  }
  __shared__ float red[2048];
#pragma unroll
  for (int j = 0; j < 8; ++j) red[t * 8 + j] = acc[j];
  __syncthreads();
  if (t < 64) {
    int cop = t >> 3, cj = t & 7;
    float o = 0.f;
    for (int q = 0; q < 32; ++q) o += red[(q * 8 + cop) * 8 + cj];
    atomicAdd(&sums[g * 64 + t], o);
  }
  // last-block head
  __shared__ int lastf;
  __threadfence();
  __syncthreads();
  if (t == 0) {
    u32 tk = atomicAdd(counter, 1u);
    lastf = (tk == gridDim.x * gridDim.y - 1) ? 1 : 0;
  }
  __syncthreads();
  if (!lastf) return;
  __shared__ float ab3[128];
  if (t < 64) {
    float s1 = 0.f, s2 = 0.f;
    for (int sl = 0; sl < 32; ++sl) {
      s1 += bnacc3[sl * 128 + t];
      s2 += bnacc3[sl * 128 + 64 + t];
    }
    float mu = s1 / (float)N_NODES;
    float var = s2 / (float)N_NODES - mu * mu;
    float al = g3[t] / sqrtf(var + EPS);
    ab3[t] = al;
    ab3[64 + t] = be3[t] - mu * al;
  }
  __syncthreads();
  if (t < N_GRAPHS) {
    u32 cntn = bounds[t + 1] - bounds[t];
    float inv = (cntn > 0) ? 1.f / (float)cntn : 0.f;
    float lg[10];
#pragma unroll
    for (int j = 0; j < 10; ++j) lg[j] = bo[j];
    for (int c = 0; c < 64; ++c) {
      float sv = __hip_atomic_load(&sums[t * 64 + c], __ATOMIC_RELAXED,
                                   __HIP_MEMORY_SCOPE_AGENT);
      float p = (cntn > 0) ? (sv * inv * ab3[c] + ab3[64 + c]) : 0.f;
#pragma unroll
      for (int j = 0; j < 10; ++j) lg[j] = fmaf(p, Wo[c * 10 + j], lg[j]);
    }
    float mx = lg[0];
#pragma unroll
    for (int j = 1; j < 10; ++j) mx = fmaxf(mx, lg[j]);
    float ssum = 0.f, ex[10];
#pragma unroll
    for (int j = 0; j < 10; ++j) { ex[j] = expf(lg[j] - mx); ssum += ex[j]; }
#pragma unroll
    for (int j = 0; j < 10; ++j) out[t * 10 + j] = ex[j] / ssum;
  }
}

extern "C" void kernel_launch(void* const* d_in, const int* in_sizes, int n_in,
                              void* d_out, int out_size, void* d_ws, size_t ws_size,
                              hipStream_t stream) {
  const float* x    = (const float*)d_in[0];
  const int*   ei   = (const int*)d_in[1];
  const int*   batch= (const int*)d_in[2];
  const float* W1 = (const float*)d_in[3];  const float* b1 = (const float*)d_in[4];
  const float* W2 = (const float*)d_in[5];  const float* b2 = (const float*)d_in[6];
  const float* W3 = (const float*)d_in[7];  const float* b3 = (const float*)d_in[8];
  const float* g1 = (const float*)d_in[9];  const float* be1= (const float*)d_in[10];
  const float* g2 = (const float*)d_in[11]; const float* be2= (const float*)d_in[12];
  const float* g3 = (const float*)d_in[13]; const float* be3= (const float*)d_in[14];
  const float* Wo = (const float*)d_in[15]; const float* bo = (const float*)d_in[16];
  float* out = (float*)d_out;

  char* p = (char*)d_ws;
  auto alloc = [&](size_t bytes) { void* r = (void*)p; p += (bytes + 255) & ~(size_t)255; return r; };
  uint4* Wb     = (uint4*)alloc(3072 * sizeof(uint4));
  u32*   bounds = (u32*)alloc(65 * sizeof(u32));
  u32*   bcnt   = (u32*)alloc(NBUCK * sizeof(u32));
  u32*   boffs  = (u32*)alloc((NBUCK + 1) * sizeof(u32));
  u32*   bcur   = (u32*)alloc(NBUCK * sizeof(u32));
  u32*   cnt    = (u32*)alloc((size_t)N_NODES * sizeof(u32));
  u32*   offs   = (u32*)alloc((size_t)N_NODES * sizeof(u32));
  // contiguous zero region: sums (4096f) + bnacc (3*32*128 = 12288f) + counter
  float* sums   = (float*)alloc(4096 * sizeof(float));
  float* bnacc  = (float*)alloc(12288 * sizeof(float));
  u32*   counter= (u32*)alloc(256);
  u32*   esrc   = (u32*)alloc((size_t)N_EDGES * sizeof(u32));
  u32*   pairs  = (u32*)alloc((size_t)N_EDGES * sizeof(u32));
  ushort* ub    = (ushort*)alloc((size_t)N_NODES * 64 * sizeof(ushort));
  ushort* vb    = (ushort*)alloc((size_t)N_NODES * 64 * sizeof(ushort));
  ushort* hb    = (ushort*)alloc((size_t)N_NODES * 64 * sizeof(ushort));

  const int* src = ei;
  const int* dst = ei + N_EDGES;

  hipMemsetAsync(bcnt, 0, NBUCK * sizeof(u32), stream);
  // setup: bhist (782) + weight pack (12) + bounds (1) + zero accumulators (1)
  setup_k<<<EBLK + 14, 256, 0, stream>>>(dst, bcnt, W1, W2, W3, Wb, batch, bounds,
                                         (u32*)sums);
  bscan_k<<<1, 512, 0, stream>>>(bcnt, boffs, bcur);
  bscat_k<<<BSCAT_GRID, 256, 0, stream>>>(src, dst, bcur, pairs);

  // fscat2 || layer-1 GEMM
  fused_fg_k<<<NBUCK + GEMM_TILES, 256, 0, stream>>>(boffs, pairs, esrc, offs, cnt,
                                                     x, Wb, b1, ub, vb);
  segmax_k<<<SEG_NBLK, 256, 0, stream>>>(vb, offs, cnt, esrc, ub, hb, bnacc);

  // ---- layer 2 ----
  gemm_k<<<GEMM_TILES, 256, 0, stream>>>(hb, Wb + 1024, bnacc, g1, be1, b2, ub, vb);
  segmax_k<<<SEG_NBLK, 256, 0, stream>>>(vb, offs, cnt, esrc, ub, hb, bnacc + 4096);

  // ---- layer 3 ----
  gemm_k<<<GEMM_TILES, 256, 0, stream>>>(hb, Wb + 2048, bnacc + 4096, g2, be2, b3, ub, vb);
  segmax_k<<<SEG_NBLK, 256, 0, stream>>>(vb, offs, cnt, esrc, ub, hb, bnacc + 8192);

  // ---- pool + BN3 + head (last-block pattern) ----
  pool_head_k<<<dim3(32, N_GRAPHS), 256, 0, stream>>>(hb, bounds, sums, bnacc + 8192,
                                                      g3, be3, Wo, bo, counter, out);
}

// Round 11
// 225.718 us; speedup vs baseline: 1.6258x; 1.6258x over previous
//
#include <hip/hip_runtime.h>
#include <hip/hip_bf16.h>
#include <math.h>

#define N_NODES 100000
#define N_EDGES 1600000
#define N_GRAPHS 64
#define EPS 1e-5f
#define NBUCK 391       // ceil(N_NODES / 256)
#define EBLK 782        // ceil(N_EDGES / 2048)  (setup bhist blocks)
#define BSCAT_GRID 196  // ceil(N_EDGES / 8192)
#define SEG_NBLK 3125   // 3125 * 32 = 100000 node slots (exact)
#define GEMM_TILES 1563 // ceil(N_NODES / 64)

typedef unsigned int u32;
typedef __attribute__((ext_vector_type(8))) short short8;
typedef __attribute__((ext_vector_type(4))) float f32x4;

static __device__ __forceinline__ ushort f2bf(float f) {
  u32 x = __float_as_uint(f);
  u32 r = (x + 0x7fffu + ((x >> 16) & 1u)) >> 16;  // RNE; inputs finite
  return (ushort)r;
}
static __device__ __forceinline__ float bflo(u32 w) { return __uint_as_float(w << 16); }
static __device__ __forceinline__ float bfhi(u32 w) { return __uint_as_float(w & 0xffff0000u); }
static __device__ __forceinline__ void decode8(uint4 w, float* f) {
  f[0] = bflo(w.x); f[1] = bfhi(w.x); f[2] = bflo(w.y); f[3] = bfhi(w.y);
  f[4] = bflo(w.z); f[5] = bfhi(w.z); f[6] = bflo(w.w); f[7] = bfhi(w.w);
}

// ---------- setup: bhist + weight pack + graph bounds + zero accumulators ----------
// Wb[layer][kh(2)][ct(8)][lane(64)] = uint4 (8 bf16): lane l, elem j ->
//   Wc[kh*32 + (l>>4)*8 + j][ct*16 + (l&15)], Wc = [A-B | B] (64 x 128)
__global__ __launch_bounds__(256) void setup_k(
    const int* __restrict__ dst, u32* __restrict__ bcnt,
    const float* __restrict__ W1, const float* __restrict__ W2,
    const float* __restrict__ W3, uint4* __restrict__ Wb,
    const int* __restrict__ batch, u32* __restrict__ bounds,
    u32* __restrict__ zbase) {
  __shared__ u32 csh[NBUCK];
  int bid = blockIdx.x, t = threadIdx.x;
  if (bid < EBLK) {
    for (int i = t; i < NBUCK; i += 256) csh[i] = 0;
    __syncthreads();
    int base = bid * 2048;
#pragma unroll
    for (int k = 0; k < 8; ++k) {
      int e = base + k * 256 + t;
      if (e < N_EDGES) atomicAdd(&csh[(u32)dst[e] >> 8], 1u);
    }
    __syncthreads();
    for (int i = t; i < NBUCK; i += 256) {
      u32 cc = csh[i];
      if (cc) atomicAdd(&bcnt[i], cc);
    }
  } else if (bid < EBLK + 12) {
    int g = (bid - EBLK) * 256 + t;
    if (g >= 3072) return;
    int layer = g >> 10, rem = g & 1023;
    int kh = rem >> 9, ct = (rem >> 6) & 7, l = rem & 63;
    const float* W = (layer == 0) ? W1 : (layer == 1) ? W2 : W3;
    int c = ct * 16 + (l & 15);
    u32 w[4];
#pragma unroll
    for (int jj = 0; jj < 4; ++jj) {
      int k0 = kh * 32 + (l >> 4) * 8 + 2 * jj;
      float v0, v1;
      if (c < 64) {
        v0 = W[k0 * 64 + c] - W[(64 + k0) * 64 + c];
        v1 = W[(k0 + 1) * 64 + c] - W[(65 + k0) * 64 + c];
      } else {
        v0 = W[(64 + k0) * 64 + (c - 64)];
        v1 = W[(65 + k0) * 64 + (c - 64)];
      }
      w[jj] = (u32)f2bf(v0) | ((u32)f2bf(v1) << 16);
    }
    Wb[g] = make_uint4(w[0], w[1], w[2], w[3]);
  } else if (bid == EBLK + 12) {
    if (t > 64) return;
    int lo = 0, hi = N_NODES;
    while (lo < hi) {
      int mid = (lo + hi) >> 1;
      if (batch[mid] < t) lo = mid + 1; else hi = mid;
    }
    bounds[t] = (u32)lo;
  } else {
    // zero sums (4096) + bnacc (12288) + counter region (64)
    for (int i = t; i < 16448; i += 256) zbase[i] = 0u;
  }
}

// ---------- bucket scan -> boffs (exclusive, +total), bcur ----------
__global__ void bscan_k(const u32* __restrict__ bcnt, u32* __restrict__ boffs,
                        u32* __restrict__ bcur) {
  __shared__ u32 s[512];
  int t = threadIdx.x;
  u32 v = (t < NBUCK) ? bcnt[t] : 0u;
  s[t] = v;
  __syncthreads();
  for (int d = 1; d < 512; d <<= 1) {
    u32 a = (t >= d) ? s[t - d] : 0u;
    __syncthreads();
    s[t] += a;
    __syncthreads();
  }
  if (t < NBUCK) { boffs[t] = s[t] - v; bcur[t] = s[t] - v; }
  if (t == NBUCK - 1) boffs[NBUCK] = s[t];
}

// ---------- pass C: edges -> bucket-grouped packed pairs ((dst&255)<<24 | src) ----------
// 8192 edges/block (32/thread in registers) for write-combining on bucket fronts.
__global__ __launch_bounds__(256) void bscat_k(const int* __restrict__ src,
                                               const int* __restrict__ dst,
                                               u32* __restrict__ gcur,
                                               u32* __restrict__ pairs) {
  __shared__ u32 cnt[NBUCK];
  __shared__ u32 base[NBUCK];
  int t = threadIdx.x;
  for (int i = t; i < NBUCK; i += 256) cnt[i] = 0;
  __syncthreads();
  u32 pk[32], bk[32];
  int be = blockIdx.x * 8192;
#pragma unroll
  for (int k = 0; k < 32; ++k) {
    int e = be + k * 256 + t;
    if (e < N_EDGES) {
      u32 d = (u32)dst[e], s = (u32)src[e];
      u32 b = d >> 8;
      pk[k] = ((d & 255u) << 24) | s;
      bk[k] = b;
      atomicAdd(&cnt[b], 1u);
    } else bk[k] = 0xFFFFFFFFu;
  }
  __syncthreads();
  for (int i = t; i < NBUCK; i += 256) {
    u32 c = cnt[i];
    base[i] = c ? atomicAdd(&gcur[i], c) : 0u;
    cnt[i] = 0;
  }
  __syncthreads();
#pragma unroll
  for (int k = 0; k < 32; ++k) {
    if (bk[k] != 0xFFFFFFFFu) {
      u32 p = base[bk[k]] + atomicAdd(&cnt[bk[k]], 1u);
      pairs[p] = pk[k];
    }
  }
}

// ---------- fscat2 body: per-bucket node CSR (LDS hist+scan) + place ----------
static __device__ __forceinline__ void fscat2_body(
    int b, u32* SH, const u32* __restrict__ boffs, const u32* __restrict__ pairs,
    u32* __restrict__ esrc, u32* __restrict__ offs_g, u32* __restrict__ cnt_g) {
  u32* lcnt = SH; u32* lexc = SH + 256; u32* lcur = SH + 512;
  int t = threadIdx.x;
  u32 s0 = boffs[b], e0 = boffs[b + 1];
  lcnt[t] = 0;
  __syncthreads();
  for (u32 p = s0 + t; p < e0; p += 256) atomicAdd(&lcnt[pairs[p] >> 24], 1u);
  __syncthreads();
  u32 v = lcnt[t];
  lexc[t] = v;
  __syncthreads();
  for (int d = 1; d < 256; d <<= 1) {
    u32 a = (t >= d) ? lexc[t - d] : 0u;
    __syncthreads();
    lexc[t] += a;
    __syncthreads();
  }
  u32 excl = lexc[t] - v;
  int node = (b << 8) + t;
  if (node < N_NODES) { offs_g[node] = s0 + excl; cnt_g[node] = v; }
  lcur[t] = 0;
  lexc[t] = excl;
  __syncthreads();
  for (u32 p = s0 + t; p < e0; p += 256) {
    u32 pk = pairs[p];
    u32 dl = pk >> 24;
    u32 l = atomicAdd(&lcur[dl], 1u);
    esrc[s0 + lexc[dl] + l] = pk & 0x00FFFFFFu;
  }
}

// ---------- MFMA GEMM body: [u | v] = act(X) @ [A-B | B], u/v bf16 out ----------
// One 64-row tile; 4 waves; Xl XOR-swizzled (byte^=(row&7)<<4).
static __device__ __forceinline__ void gemm_body(
    int tile, u32* Xl,
    const void* __restrict__ xin, int xbf16, const uint4* __restrict__ Wb,
    const float* ab, const float* __restrict__ bias,
    ushort* __restrict__ ub, ushort* __restrict__ vb) {
  int t = threadIdx.x;
  int l = t & 63, wv = t >> 6;
  short8 bs[2][8];
#pragma unroll
  for (int kh = 0; kh < 2; ++kh)
#pragma unroll
    for (int ct = 0; ct < 8; ++ct) {
      uint4 tmp = Wb[(kh * 8 + ct) * 64 + l];
      __builtin_memcpy(&bs[kh][ct], &tmp, 16);
    }
  int srow = t >> 2, scol = (t & 3) * 16;
  int rb = tile * 64;
  int gr = rb + srow;
  u32 xb[8];
  if (gr < N_NODES) {
    if (xbf16) {
      const uint4* xp = (const uint4*)((const ushort*)xin + (size_t)gr * 64 + scol);
      uint4 p0 = xp[0], p1 = xp[1];
      u32 raw[8] = {p0.x, p0.y, p0.z, p0.w, p1.x, p1.y, p1.z, p1.w};
#pragma unroll
      for (int q = 0; q < 8; ++q) {
        int c = scol + 2 * q;
        float lo = fmaxf(fmaf(bflo(raw[q]), ab[c], ab[64 + c]), 0.f);
        float hi = fmaxf(fmaf(bfhi(raw[q]), ab[c + 1], ab[64 + c + 1]), 0.f);
        xb[q] = (u32)f2bf(lo) | ((u32)f2bf(hi) << 16);
      }
    } else {
      const float4* xp = (const float4*)((const float*)xin + (size_t)gr * 64 + scol);
#pragma unroll
      for (int q = 0; q < 4; ++q) {
        float4 a = xp[q];
        xb[2 * q]     = (u32)f2bf(a.x) | ((u32)f2bf(a.y) << 16);
        xb[2 * q + 1] = (u32)f2bf(a.z) | ((u32)f2bf(a.w) << 16);
      }
    }
  } else {
#pragma unroll
    for (int q = 0; q < 8; ++q) xb[q] = 0u;
  }
  int byte0 = srow * 128 + ((scol * 2) ^ ((srow & 7) << 4));
  int byte1 = srow * 128 + ((scol * 2 + 16) ^ ((srow & 7) << 4));
  *(uint4*)((char*)Xl + byte0) = make_uint4(xb[0], xb[1], xb[2], xb[3]);
  *(uint4*)((char*)Xl + byte1) = make_uint4(xb[4], xb[5], xb[6], xb[7]);
  __syncthreads();
  f32x4 acc[8];
#pragma unroll
  for (int ct = 0; ct < 8; ++ct) {
    float b0 = (ct < 4) ? bias[ct * 16 + (l & 15)] : 0.f;
    acc[ct] = (f32x4){b0, b0, b0, b0};
  }
  int arow = wv * 16 + (l & 15);
#pragma unroll
  for (int kh = 0; kh < 2; ++kh) {
    int abyte = arow * 128 + ((kh * 64 + ((l >> 4) * 16)) ^ ((arow & 7) << 4));
    short8 af = *(const short8*)((const char*)Xl + abyte);
#pragma unroll
    for (int ct = 0; ct < 8; ++ct)
      acc[ct] = __builtin_amdgcn_mfma_f32_16x16x32_bf16(af, bs[kh][ct], acc[ct], 0, 0, 0);
  }
  // C layout: col = l&15, row = 4*(l>>4)+reg (m89-verified)
  int rloc = rb + wv * 16 + 4 * (l >> 4);
#pragma unroll
  for (int ct = 0; ct < 4; ++ct) {
    int col = ct * 16 + (l & 15);
#pragma unroll
    for (int r = 0; r < 4; ++r) {
      int row = rloc + r;
      if (row < N_NODES) ub[(size_t)row * 64 + col] = f2bf(acc[ct][r]);
    }
  }
#pragma unroll
  for (int ct = 4; ct < 8; ++ct) {
    int col = ct * 16 + (l & 15) - 64;
#pragma unroll
    for (int r = 0; r < 4; ++r) {
      int row = rloc + r;
      if (row < N_NODES) vb[(size_t)row * 64 + col] = f2bf(acc[ct][r]);
    }
  }
}

// ---------- fused: fscat2 (391 blocks) || layer-1 GEMM (1563 blocks) ----------
__global__ __launch_bounds__(256) void fused_fg_k(
    const u32* __restrict__ boffs, const u32* __restrict__ pairs,
    u32* __restrict__ esrc, u32* __restrict__ offs_g, u32* __restrict__ cnt_g,
    const float* __restrict__ x, const uint4* __restrict__ Wb,
    const float* __restrict__ bias, ushort* __restrict__ ub, ushort* __restrict__ vb) {
  __shared__ u32 SH[2048];  // 8KB
  int bid = blockIdx.x;
  if (bid < NBUCK) fscat2_body(bid, SH, boffs, pairs, esrc, offs_g, cnt_g);
  else gemm_body(bid - NBUCK, SH, x, 0, Wb, nullptr, bias, ub, vb);
}

// ---------- standalone GEMM (layers 2,3): BN affine computed from bnacc slices ----------
__global__ __launch_bounds__(256) void gemm_k(
    const ushort* __restrict__ xin, const uint4* __restrict__ Wb,
    const float* __restrict__ bnacc, const float* __restrict__ g,
    const float* __restrict__ be, const float* __restrict__ bias,
    ushort* __restrict__ ub, ushort* __restrict__ vb) {
  __shared__ u32 Xl[2048];
  __shared__ float ab_sh[128];
  int t = threadIdx.x;
  if (t < 64) {
    float s1 = 0.f, s2 = 0.f;
    for (int s = 0; s < 32; ++s) {
      s1 += bnacc[s * 128 + t];
      s2 += bnacc[s * 128 + 64 + t];
    }
    float mu = s1 / (float)N_NODES;
    float var = s2 / (float)N_NODES - mu * mu;
    float al = g[t] / sqrtf(var + EPS);
    ab_sh[t] = al;
    ab_sh[64 + t] = be[t] - mu * al;
  }
  __syncthreads();
  gemm_body(blockIdx.x, Xl, xin, 1, Wb, ab_sh, bias, ub, vb);
}

// ---------- segmax: 1 node/slot, 8 lanes/node, uint4 gathers, unroll-4 ----------
// h = relu(u + max) bf16; BN partials -> sliced global accumulators (float atomics)
__global__ __launch_bounds__(256) void segmax_k(
    const ushort* __restrict__ v, const u32* __restrict__ offs,
    const u32* __restrict__ cnt, const u32* __restrict__ esrc,
    const ushort* __restrict__ ub, ushort* __restrict__ hb,
    float* __restrict__ bnacc) {
  int t = threadIdx.x;
  int lane = t & 63;
  int op = lane & 7;        // uint4 index within row (8 channels)
  int sub = lane >> 3;      // node sub-group within wave
  int wv = t >> 6;
  int node = blockIdx.x * 32 + wv * 8 + sub;   // grid*32 == N_NODES exactly
  const uint4* v4 = (const uint4*)v;
  const uint4* u4 = (const uint4*)ub;
  uint4* h4 = (uint4*)hb;
  u32 off = offs[node], deg = cnt[node];
  const u32* ep = esrc + off;
  float m[8];
#pragma unroll
  for (int j = 0; j < 8; ++j) m[j] = -INFINITY;
  u32 i = 0;
  for (; i + 4 <= deg; i += 4) {
    u32 sA = ep[i], sB = ep[i + 1], sC = ep[i + 2], sD = ep[i + 3];
    uint4 wA = v4[(size_t)sA * 8 + op];
    uint4 wB = v4[(size_t)sB * 8 + op];
    uint4 wC = v4[(size_t)sC * 8 + op];
    uint4 wD = v4[(size_t)sD * 8 + op];
    float fA[8], fB[8], fC[8], fD[8];
    decode8(wA, fA); decode8(wB, fB); decode8(wC, fC); decode8(wD, fD);
#pragma unroll
    for (int j = 0; j < 8; ++j)
      m[j] = fmaxf(fmaxf(m[j], fmaxf(fA[j], fB[j])), fmaxf(fC[j], fD[j]));
  }
  for (; i < deg; ++i) {
    uint4 w = v4[(size_t)ep[i] * 8 + op];
    float f[8]; decode8(w, f);
#pragma unroll
    for (int j = 0; j < 8; ++j) m[j] = fmaxf(m[j], f[j]);
  }
  uint4 uu = u4[(size_t)node * 8 + op];
  float uf[8]; decode8(uu, uf);
  float h[8];
#pragma unroll
  for (int j = 0; j < 8; ++j) h[j] = fmaxf(uf[j] + m[j], 0.f);  // relu(-inf)=0
  uint4 hw;
  hw.x = (u32)f2bf(h[0]) | ((u32)f2bf(h[1]) << 16);
  hw.y = (u32)f2bf(h[2]) | ((u32)f2bf(h[3]) << 16);
  hw.z = (u32)f2bf(h[4]) | ((u32)f2bf(h[5]) << 16);
  hw.w = (u32)f2bf(h[6]) | ((u32)f2bf(h[7]) << 16);
  h4[(size_t)node * 8 + op] = hw;
  // BN partials: channel c = op*8 + j; reduce 32 nodes per block
  __shared__ float red[2048];
#pragma unroll
  for (int j = 0; j < 8; ++j) red[t * 8 + j] = h[j];
  __syncthreads();
  float o1 = 0.f, o2 = 0.f;
  if (t < 64) {
    int cop = t >> 3, cj = t & 7;
    for (int q = 0; q < 32; ++q) o1 += red[(q * 8 + cop) * 8 + cj];
  }
  __syncthreads();
#pragma unroll
  for (int j = 0; j < 8; ++j) red[t * 8 + j] = h[j] * h[j];
  __syncthreads();
  if (t < 64) {
    int cop = t >> 3, cj = t & 7;
    for (int q = 0; q < 32; ++q) o2 += red[(q * 8 + cop) * 8 + cj];
    int slice = blockIdx.x & 31;
    atomicAdd(&bnacc[slice * 128 + t], o1);
    atomicAdd(&bnacc[slice * 128 + 64 + t], o2);
  }
}

// ---------- pool partials: uint4 loads, 8 lanes/node, no fence ----------
__global__ __launch_bounds__(256) void pool_part_k(
    const ushort* __restrict__ h3, const u32* __restrict__ bounds,
    float* __restrict__ sums) {
  int g = blockIdx.y;
  u32 s = bounds[g], e = bounds[g + 1];
  int t = threadIdx.x;
  int op = t & 7;                       // uint4 index (8 channels)
  int slot = blockIdx.x * 32 + (t >> 3);
  int nsl = gridDim.x * 32;             // 512 node slots per graph
  const uint4* h4 = (const uint4*)h3;
  float acc[8];
#pragma unroll
  for (int j = 0; j < 8; ++j) acc[j] = 0.f;
  for (u32 n = s + slot; n < e; n += nsl) {
    uint4 w = h4[(size_t)n * 8 + op];
    float f[8]; decode8(w, f);
#pragma unroll
    for (int j = 0; j < 8; ++j) acc[j] += f[j];
  }
  __shared__ float red[2048];
#pragma unroll
  for (int j = 0; j < 8; ++j) red[t * 8 + j] = acc[j];
  __syncthreads();
  if (t < 64) {
    int cop = t >> 3, cj = t & 7;
    float o = 0.f;
    for (int q = 0; q < 32; ++q) o += red[(q * 8 + cop) * 8 + cj];
    atomicAdd(&sums[g * 64 + t], o);
  }
}

// ---------- head: BN3 affine + mean + linear + softmax (1 block) ----------
__global__ void head_k(const float* __restrict__ sums, const u32* __restrict__ bounds,
                       const float* __restrict__ bnacc3, const float* __restrict__ g3,
                       const float* __restrict__ be3, const float* __restrict__ Wo,
                       const float* __restrict__ bo, float* __restrict__ out) {
  __shared__ float ab3[128];
  int t = threadIdx.x;
  if (t < 64) {
    float s1 = 0.f, s2 = 0.f;
    for (int sl = 0; sl < 32; ++sl) {
      s1 += bnacc3[sl * 128 + t];
      s2 += bnacc3[sl * 128 + 64 + t];
    }
    float mu = s1 / (float)N_NODES;
    float var = s2 / (float)N_NODES - mu * mu;
    float al = g3[t] / sqrtf(var + EPS);
    ab3[t] = al;
    ab3[64 + t] = be3[t] - mu * al;
  }
  __syncthreads();
  if (t >= N_GRAPHS) return;
  u32 cntn = bounds[t + 1] - bounds[t];
  float inv = (cntn > 0) ? 1.f / (float)cntn : 0.f;
  float lg[10];
#pragma unroll
  for (int j = 0; j < 10; ++j) lg[j] = bo[j];
  for (int c = 0; c < 64; ++c) {
    float p = (cntn > 0) ? (sums[t * 64 + c] * inv * ab3[c] + ab3[64 + c]) : 0.f;
#pragma unroll
    for (int j = 0; j < 10; ++j) lg[j] = fmaf(p, Wo[c * 10 + j], lg[j]);
  }
  float mx = lg[0];
#pragma unroll
  for (int j = 1; j < 10; ++j) mx = fmaxf(mx, lg[j]);
  float ssum = 0.f, ex[10];
#pragma unroll
  for (int j = 0; j < 10; ++j) { ex[j] = expf(lg[j] - mx); ssum += ex[j]; }
#pragma unroll
  for (int j = 0; j < 10; ++j) out[t * 10 + j] = ex[j] / ssum;
}

extern "C" void kernel_launch(void* const* d_in, const int* in_sizes, int n_in,
                              void* d_out, int out_size, void* d_ws, size_t ws_size,
                              hipStream_t stream) {
  const float* x    = (const float*)d_in[0];
  const int*   ei   = (const int*)d_in[1];
  const int*   batch= (const int*)d_in[2];
  const float* W1 = (const float*)d_in[3];  const float* b1 = (const float*)d_in[4];
  const float* W2 = (const float*)d_in[5];  const float* b2 = (const float*)d_in[6];
  const float* W3 = (const float*)d_in[7];  const float* b3 = (const float*)d_in[8];
  const float* g1 = (const float*)d_in[9];  const float* be1= (const float*)d_in[10];
  const float* g2 = (const float*)d_in[11]; const float* be2= (const float*)d_in[12];
  const float* g3 = (const float*)d_in[13]; const float* be3= (const float*)d_in[14];
  const float* Wo = (const float*)d_in[15]; const float* bo = (const float*)d_in[16];
  float* out = (float*)d_out;

  char* p = (char*)d_ws;
  auto alloc = [&](size_t bytes) { void* r = (void*)p; p += (bytes + 255) & ~(size_t)255; return r; };
  uint4* Wb     = (uint4*)alloc(3072 * sizeof(uint4));
  u32*   bounds = (u32*)alloc(65 * sizeof(u32));
  u32*   bcnt   = (u32*)alloc(NBUCK * sizeof(u32));
  u32*   boffs  = (u32*)alloc((NBUCK + 1) * sizeof(u32));
  u32*   bcur   = (u32*)alloc(NBUCK * sizeof(u32));
  u32*   cnt    = (u32*)alloc((size_t)N_NODES * sizeof(u32));
  u32*   offs   = (u32*)alloc((size_t)N_NODES * sizeof(u32));
  // contiguous zero region: sums (4096f) + bnacc (3*32*128 = 12288f) + spare
  float* sums   = (float*)alloc(4096 * sizeof(float));
  float* bnacc  = (float*)alloc(12288 * sizeof(float));
  u32*   spare  = (u32*)alloc(256);
  (void)spare;
  u32*   esrc   = (u32*)alloc((size_t)N_EDGES * sizeof(u32));
  u32*   pairs  = (u32*)alloc((size_t)N_EDGES * sizeof(u32));
  ushort* ub    = (ushort*)alloc((size_t)N_NODES * 64 * sizeof(ushort));
  ushort* vb    = (ushort*)alloc((size_t)N_NODES * 64 * sizeof(ushort));
  ushort* hb    = (ushort*)alloc((size_t)N_NODES * 64 * sizeof(ushort));

  const int* src = ei;
  const int* dst = ei + N_EDGES;

  hipMemsetAsync(bcnt, 0, NBUCK * sizeof(u32), stream);
  // setup: bhist (782) + weight pack (12) + bounds (1) + zero accumulators (1)
  setup_k<<<EBLK + 14, 256, 0, stream>>>(dst, bcnt, W1, W2, W3, Wb, batch, bounds,
                                         (u32*)sums);
  bscan_k<<<1, 512, 0, stream>>>(bcnt, boffs, bcur);
  bscat_k<<<BSCAT_GRID, 256, 0, stream>>>(src, dst, bcur, pairs);

  // fscat2 || layer-1 GEMM
  fused_fg_k<<<NBUCK + GEMM_TILES, 256, 0, stream>>>(boffs, pairs, esrc, offs, cnt,
                                                     x, Wb, b1, ub, vb);
  segmax_k<<<SEG_NBLK, 256, 0, stream>>>(vb, offs, cnt, esrc, ub, hb, bnacc);

  // ---- layer 2 ----
  gemm_k<<<GEMM_TILES, 256, 0, stream>>>(hb, Wb + 1024, bnacc, g1, be1, b2, ub, vb);
  segmax_k<<<SEG_NBLK, 256, 0, stream>>>(vb, offs, cnt, esrc, ub, hb, bnacc + 4096);

  // ---- layer 3 ----
  gemm_k<<<GEMM_TILES, 256, 0, stream>>>(hb, Wb + 2048, bnacc + 4096, g2, be2, b3, ub, vb);
  segmax_k<<<SEG_NBLK, 256, 0, stream>>>(vb, offs, cnt, esrc, ub, hb, bnacc + 8192);

  // ---- pool + head ----
  pool_part_k<<<dim3(16, N_GRAPHS), 256, 0, stream>>>(hb, bounds, sums);
  head_k<<<1, 64, 0, stream>>>(sums, bounds, bnacc + 8192, g3, be3, Wo, bo, out);
}

// Round 12
// 205.509 us; speedup vs baseline: 1.7857x; 1.0983x over previous
//
#include <hip/hip_runtime.h>
#include <hip/hip_bf16.h>
#include <math.h>

#define N_NODES 100000
#define N_EDGES 1600000
#define N_GRAPHS 64
#define EPS 1e-5f
#define NBUCK 391       // ceil(N_NODES / 256)
#define BSTRIDE 6144    // fixed per-bucket region (mean 4096, sigma~64)
#define BSCAT_GRID 196  // ceil(N_EDGES / 8192)
#define SEG_NBLK 3125   // 3125 * 32 = 100000 node slots (exact)
#define GEMM_TILES 1563 // ceil(N_NODES / 64)

typedef unsigned int u32;
typedef __attribute__((ext_vector_type(8))) short short8;
typedef __attribute__((ext_vector_type(4))) float f32x4;

static __device__ __forceinline__ ushort f2bf(float f) {
  u32 x = __float_as_uint(f);
  u32 r = (x + 0x7fffu + ((x >> 16) & 1u)) >> 16;  // RNE; inputs finite
  return (ushort)r;
}
static __device__ __forceinline__ float bflo(u32 w) { return __uint_as_float(w << 16); }
static __device__ __forceinline__ float bfhi(u32 w) { return __uint_as_float(w & 0xffff0000u); }
static __device__ __forceinline__ void decode8(uint4 w, float* f) {
  f[0] = bflo(w.x); f[1] = bfhi(w.x); f[2] = bflo(w.y); f[3] = bfhi(w.y);
  f[4] = bflo(w.z); f[5] = bfhi(w.z); f[6] = bflo(w.w); f[7] = bfhi(w.w);
}

// ---------- pass C + setup: blocks [0,196) scatter edges into fixed-stride
// bucket regions; blocks [196,208) pack weights; 208 = bounds; 209 = zeroing.
// Wb[layer][kh(2)][ct(8)][lane(64)] = uint4 (8 bf16): lane l, elem j ->
//   Wc[kh*32 + (l>>4)*8 + j][ct*16 + (l&15)], Wc = [A-B | B] (64 x 128)
__global__ __launch_bounds__(256) void bscat_setup_k(
    const int* __restrict__ src, const int* __restrict__ dst,
    u32* __restrict__ bcur, u32* __restrict__ pairs,
    const float* __restrict__ W1, const float* __restrict__ W2,
    const float* __restrict__ W3, uint4* __restrict__ Wb,
    const int* __restrict__ batch, u32* __restrict__ bounds,
    u32* __restrict__ zbase) {
  __shared__ u32 cnt[NBUCK];
  __shared__ u32 base[NBUCK];
  int bid = blockIdx.x, t = threadIdx.x;
  if (bid < BSCAT_GRID) {
    for (int i = t; i < NBUCK; i += 256) cnt[i] = 0;
    __syncthreads();
    u32 pk[32], bk[32];
    int be = bid * 8192;
#pragma unroll
    for (int k = 0; k < 32; ++k) {
      int e = be + k * 256 + t;
      if (e < N_EDGES) {
        u32 d = (u32)dst[e], s = (u32)src[e];
        u32 b = d >> 8;
        pk[k] = ((d & 255u) << 24) | s;
        bk[k] = b;
        atomicAdd(&cnt[b], 1u);
      } else bk[k] = 0xFFFFFFFFu;
    }
    __syncthreads();
    for (int i = t; i < NBUCK; i += 256) {
      u32 c = cnt[i];
      base[i] = c ? (i * BSTRIDE + atomicAdd(&bcur[i], c)) : 0u;
      cnt[i] = 0;
    }
    __syncthreads();
#pragma unroll
    for (int k = 0; k < 32; ++k) {
      if (bk[k] != 0xFFFFFFFFu) {
        u32 p = base[bk[k]] + atomicAdd(&cnt[bk[k]], 1u);
        pairs[p] = pk[k];
      }
    }
  } else if (bid < BSCAT_GRID + 12) {
    int g = (bid - BSCAT_GRID) * 256 + t;
    if (g >= 3072) return;
    int layer = g >> 10, rem = g & 1023;
    int kh = rem >> 9, ct = (rem >> 6) & 7, l = rem & 63;
    const float* W = (layer == 0) ? W1 : (layer == 1) ? W2 : W3;
    int c = ct * 16 + (l & 15);
    u32 w[4];
#pragma unroll
    for (int jj = 0; jj < 4; ++jj) {
      int k0 = kh * 32 + (l >> 4) * 8 + 2 * jj;
      float v0, v1;
      if (c < 64) {
        v0 = W[k0 * 64 + c] - W[(64 + k0) * 64 + c];
        v1 = W[(k0 + 1) * 64 + c] - W[(65 + k0) * 64 + c];
      } else {
        v0 = W[(64 + k0) * 64 + (c - 64)];
        v1 = W[(65 + k0) * 64 + (c - 64)];
      }
      w[jj] = (u32)f2bf(v0) | ((u32)f2bf(v1) << 16);
    }
    Wb[g] = make_uint4(w[0], w[1], w[2], w[3]);
  } else if (bid == BSCAT_GRID + 12) {
    if (t > 64) return;
    int lo = 0, hi = N_NODES;
    while (lo < hi) {
      int mid = (lo + hi) >> 1;
      if (batch[mid] < t) lo = mid + 1; else hi = mid;
    }
    bounds[t] = (u32)lo;
  } else {
    // zero sums (4096) + bnacc (12288)
    for (int i = t; i < 16448; i += 256) zbase[i] = 0u;
  }
}

// ---------- fscat2 body: per-bucket node CSR (LDS hist+scan) + place ----------
static __device__ __forceinline__ void fscat2_body(
    int b, u32* SH, const u32* __restrict__ bcur, const u32* __restrict__ pairs,
    u32* __restrict__ esrc, u32* __restrict__ offs_g, u32* __restrict__ cnt_g) {
  u32* lcnt = SH; u32* lexc = SH + 256; u32* lcur = SH + 512;
  int t = threadIdx.x;
  u32 s0 = b * BSTRIDE, e0 = s0 + bcur[b];
  lcnt[t] = 0;
  __syncthreads();
  for (u32 p = s0 + t; p < e0; p += 256) atomicAdd(&lcnt[pairs[p] >> 24], 1u);
  __syncthreads();
  u32 v = lcnt[t];
  lexc[t] = v;
  __syncthreads();
  for (int d = 1; d < 256; d <<= 1) {
    u32 a = (t >= d) ? lexc[t - d] : 0u;
    __syncthreads();
    lexc[t] += a;
    __syncthreads();
  }
  u32 excl = lexc[t] - v;
  int node = (b << 8) + t;
  if (node < N_NODES) { offs_g[node] = s0 + excl; cnt_g[node] = v; }
  lcur[t] = 0;
  lexc[t] = excl;
  __syncthreads();
  for (u32 p = s0 + t; p < e0; p += 256) {
    u32 pk = pairs[p];
    u32 dl = pk >> 24;
    u32 l = atomicAdd(&lcur[dl], 1u);
    esrc[s0 + lexc[dl] + l] = pk & 0x00FFFFFFu;
  }
}

// ---------- MFMA GEMM body: [u | v] = act(X) @ [A-B | B], u/v bf16 out ----------
// One 64-row tile; 4 waves; Xl XOR-swizzled (byte^=(row&7)<<4).
static __device__ __forceinline__ void gemm_body(
    int tile, u32* Xl,
    const void* __restrict__ xin, int xbf16, const uint4* __restrict__ Wb,
    const float* ab, const float* __restrict__ bias,
    ushort* __restrict__ ub, ushort* __restrict__ vb) {
  int t = threadIdx.x;
  int l = t & 63, wv = t >> 6;
  short8 bs[2][8];
#pragma unroll
  for (int kh = 0; kh < 2; ++kh)
#pragma unroll
    for (int ct = 0; ct < 8; ++ct) {
      uint4 tmp = Wb[(kh * 8 + ct) * 64 + l];
      __builtin_memcpy(&bs[kh][ct], &tmp, 16);
    }
  int srow = t >> 2, scol = (t & 3) * 16;
  int rb = tile * 64;
  int gr = rb + srow;
  u32 xb[8];
  if (gr < N_NODES) {
    if (xbf16) {
      const uint4* xp = (const uint4*)((const ushort*)xin + (size_t)gr * 64 + scol);
      uint4 p0 = xp[0], p1 = xp[1];
      u32 raw[8] = {p0.x, p0.y, p0.z, p0.w, p1.x, p1.y, p1.z, p1.w};
#pragma unroll
      for (int q = 0; q < 8; ++q) {
        int c = scol + 2 * q;
        float lo = fmaxf(fmaf(bflo(raw[q]), ab[c], ab[64 + c]), 0.f);
        float hi = fmaxf(fmaf(bfhi(raw[q]), ab[c + 1], ab[64 + c + 1]), 0.f);
        xb[q] = (u32)f2bf(lo) | ((u32)f2bf(hi) << 16);
      }
    } else {
      const float4* xp = (const float4*)((const float*)xin + (size_t)gr * 64 + scol);
#pragma unroll
      for (int q = 0; q < 4; ++q) {
        float4 a = xp[q];
        xb[2 * q]     = (u32)f2bf(a.x) | ((u32)f2bf(a.y) << 16);
        xb[2 * q + 1] = (u32)f2bf(a.z) | ((u32)f2bf(a.w) << 16);
      }
    }
  } else {
#pragma unroll
    for (int q = 0; q < 8; ++q) xb[q] = 0u;
  }
  int byte0 = srow * 128 + ((scol * 2) ^ ((srow & 7) << 4));
  int byte1 = srow * 128 + ((scol * 2 + 16) ^ ((srow & 7) << 4));
  *(uint4*)((char*)Xl + byte0) = make_uint4(xb[0], xb[1], xb[2], xb[3]);
  *(uint4*)((char*)Xl + byte1) = make_uint4(xb[4], xb[5], xb[6], xb[7]);
  __syncthreads();
  f32x4 acc[8];
#pragma unroll
  for (int ct = 0; ct < 8; ++ct) {
    float b0 = (ct < 4) ? bias[ct * 16 + (l & 15)] : 0.f;
    acc[ct] = (f32x4){b0, b0, b0, b0};
  }
  int arow = wv * 16 + (l & 15);
#pragma unroll
  for (int kh = 0; kh < 2; ++kh) {
    int abyte = arow * 128 + ((kh * 64 + ((l >> 4) * 16)) ^ ((arow & 7) << 4));
    short8 af = *(const short8*)((const char*)Xl + abyte);
#pragma unroll
    for (int ct = 0; ct < 8; ++ct)
      acc[ct] = __builtin_amdgcn_mfma_f32_16x16x32_bf16(af, bs[kh][ct], acc[ct], 0, 0, 0);
  }
  // C layout: col = l&15, row = 4*(l>>4)+reg (m89-verified)
  int rloc = rb + wv * 16 + 4 * (l >> 4);
#pragma unroll
  for (int ct = 0; ct < 4; ++ct) {
    int col = ct * 16 + (l & 15);
#pragma unroll
    for (int r = 0; r < 4; ++r) {
      int row = rloc + r;
      if (row < N_NODES) ub[(size_t)row * 64 + col] = f2bf(acc[ct][r]);
    }
  }
#pragma unroll
  for (int ct = 4; ct < 8; ++ct) {
    int col = ct * 16 + (l & 15) - 64;
#pragma unroll
    for (int r = 0; r < 4; ++r) {
      int row = rloc + r;
      if (row < N_NODES) vb[(size_t)row * 64 + col] = f2bf(acc[ct][r]);
    }
  }
}

// ---------- fused: fscat2 (391 blocks) || layer-1 GEMM (1563 blocks) ----------
__global__ __launch_bounds__(256) void fused_fg_k(
    const u32* __restrict__ bcur, const u32* __restrict__ pairs,
    u32* __restrict__ esrc, u32* __restrict__ offs_g, u32* __restrict__ cnt_g,
    const float* __restrict__ x, const uint4* __restrict__ Wb,
    const float* __restrict__ bias, ushort* __restrict__ ub, ushort* __restrict__ vb) {
  __shared__ u32 SH[2048];  // 8KB
  int bid = blockIdx.x;
  if (bid < NBUCK) fscat2_body(bid, SH, bcur, pairs, esrc, offs_g, cnt_g);
  else gemm_body(bid - NBUCK, SH, x, 0, Wb, nullptr, bias, ub, vb);
}

// ---------- standalone GEMM (layers 2,3): BN affine computed from bnacc slices ----------
__global__ __launch_bounds__(256) void gemm_k(
    const ushort* __restrict__ xin, const uint4* __restrict__ Wb,
    const float* __restrict__ bnacc, const float* __restrict__ g,
    const float* __restrict__ be, const float* __restrict__ bias,
    ushort* __restrict__ ub, ushort* __restrict__ vb) {
  __shared__ u32 Xl[2048];
  __shared__ float ab_sh[128];
  int t = threadIdx.x;
  if (t < 64) {
    float s1 = 0.f, s2 = 0.f;
    for (int s = 0; s < 32; ++s) {
      s1 += bnacc[s * 128 + t];
      s2 += bnacc[s * 128 + 64 + t];
    }
    float mu = s1 / (float)N_NODES;
    float var = s2 / (float)N_NODES - mu * mu;
    float al = g[t] / sqrtf(var + EPS);
    ab_sh[t] = al;
    ab_sh[64 + t] = be[t] - mu * al;
  }
  __syncthreads();
  gemm_body(blockIdx.x, Xl, xin, 1, Wb, ab_sh, bias, ub, vb);
}

// ---------- segmax: 1 node/slot, 8 lanes/node, uint4 gathers, unroll-4 ----------
// h = relu(u + max) bf16; BN partials -> sliced global accumulators (float atomics)
__global__ __launch_bounds__(256) void segmax_k(
    const ushort* __restrict__ v, const u32* __restrict__ offs,
    const u32* __restrict__ cnt, const u32* __restrict__ esrc,
    const ushort* __restrict__ ub, ushort* __restrict__ hb,
    float* __restrict__ bnacc) {
  int t = threadIdx.x;
  int lane = t & 63;
  int op = lane & 7;        // uint4 index within row (8 channels)
  int sub = lane >> 3;      // node sub-group within wave
  int wv = t >> 6;
  int node = blockIdx.x * 32 + wv * 8 + sub;   // grid*32 == N_NODES exactly
  const uint4* v4 = (const uint4*)v;
  const uint4* u4 = (const uint4*)ub;
  uint4* h4 = (uint4*)hb;
  u32 off = offs[node], deg = cnt[node];
  const u32* ep = esrc + off;
  float m[8];
#pragma unroll
  for (int j = 0; j < 8; ++j) m[j] = -INFINITY;
  u32 i = 0;
  for (; i + 4 <= deg; i += 4) {
    u32 sA = ep[i], sB = ep[i + 1], sC = ep[i + 2], sD = ep[i + 3];
    uint4 wA = v4[(size_t)sA * 8 + op];
    uint4 wB = v4[(size_t)sB * 8 + op];
    uint4 wC = v4[(size_t)sC * 8 + op];
    uint4 wD = v4[(size_t)sD * 8 + op];
    float fA[8], fB[8], fC[8], fD[8];
    decode8(wA, fA); decode8(wB, fB); decode8(wC, fC); decode8(wD, fD);
#pragma unroll
    for (int j = 0; j < 8; ++j)
      m[j] = fmaxf(fmaxf(m[j], fmaxf(fA[j], fB[j])), fmaxf(fC[j], fD[j]));
  }
  for (; i < deg; ++i) {
    uint4 w = v4[(size_t)ep[i] * 8 + op];
    float f[8]; decode8(w, f);
#pragma unroll
    for (int j = 0; j < 8; ++j) m[j] = fmaxf(m[j], f[j]);
  }
  uint4 uu = u4[(size_t)node * 8 + op];
  float uf[8]; decode8(uu, uf);
  float h[8];
#pragma unroll
  for (int j = 0; j < 8; ++j) h[j] = fmaxf(uf[j] + m[j], 0.f);  // relu(-inf)=0
  uint4 hw;
  hw.x = (u32)f2bf(h[0]) | ((u32)f2bf(h[1]) << 16);
  hw.y = (u32)f2bf(h[2]) | ((u32)f2bf(h[3]) << 16);
  hw.z = (u32)f2bf(h[4]) | ((u32)f2bf(h[5]) << 16);
  hw.w = (u32)f2bf(h[6]) | ((u32)f2bf(h[7]) << 16);
  h4[(size_t)node * 8 + op] = hw;
  // BN partials: channel c = op*8 + j; reduce 32 nodes per block
  __shared__ float red[2048];
#pragma unroll
  for (int j = 0; j < 8; ++j) red[t * 8 + j] = h[j];
  __syncthreads();
  float o1 = 0.f, o2 = 0.f;
  if (t < 64) {
    int cop = t >> 3, cj = t & 7;
    for (int q = 0; q < 32; ++q) o1 += red[(q * 8 + cop) * 8 + cj];
  }
  __syncthreads();
#pragma unroll
  for (int j = 0; j < 8; ++j) red[t * 8 + j] = h[j] * h[j];
  __syncthreads();
  if (t < 64) {
    int cop = t >> 3, cj = t & 7;
    for (int q = 0; q < 32; ++q) o2 += red[(q * 8 + cop) * 8 + cj];
    int slice = blockIdx.x & 31;
    atomicAdd(&bnacc[slice * 128 + t], o1);
    atomicAdd(&bnacc[slice * 128 + 64 + t], o2);
  }
}

// ---------- pool partials: uint4 loads, 8 lanes/node, no fence ----------
__global__ __launch_bounds__(256) void pool_part_k(
    const ushort* __restrict__ h3, const u32* __restrict__ bounds,
    float* __restrict__ sums) {
  int g = blockIdx.y;
  u32 s = bounds[g], e = bounds[g + 1];
  int t = threadIdx.x;
  int op = t & 7;                       // uint4 index (8 channels)
  int slot = blockIdx.x * 32 + (t >> 3);
  int nsl = gridDim.x * 32;             // 512 node slots per graph
  const uint4* h4 = (const uint4*)h3;
  float acc[8];
#pragma unroll
  for (int j = 0; j < 8; ++j) acc[j] = 0.f;
  for (u32 n = s + slot; n < e; n += nsl) {
    uint4 w = h4[(size_t)n * 8 + op];
    float f[8]; decode8(w, f);
#pragma unroll
    for (int j = 0; j < 8; ++j) acc[j] += f[j];
  }
  __shared__ float red[2048];
#pragma unroll
  for (int j = 0; j < 8; ++j) red[t * 8 + j] = acc[j];
  __syncthreads();
  if (t < 64) {
    int cop = t >> 3, cj = t & 7;
    float o = 0.f;
    for (int q = 0; q < 32; ++q) o += red[(q * 8 + cop) * 8 + cj];
    atomicAdd(&sums[g * 64 + t], o);
  }
}

// ---------- head: BN3 affine + mean + linear + softmax (1 block) ----------
__global__ void head_k(const float* __restrict__ sums, const u32* __restrict__ bounds,
                       const float* __restrict__ bnacc3, const float* __restrict__ g3,
                       const float* __restrict__ be3, const float* __restrict__ Wo,
                       const float* __restrict__ bo, float* __restrict__ out) {
  __shared__ float ab3[128];
  int t = threadIdx.x;
  if (t < 64) {
    float s1 = 0.f, s2 = 0.f;
    for (int sl = 0; sl < 32; ++sl) {
      s1 += bnacc3[sl * 128 + t];
      s2 += bnacc3[sl * 128 + 64 + t];
    }
    float mu = s1 / (float)N_NODES;
    float var = s2 / (float)N_NODES - mu * mu;
    float al = g3[t] / sqrtf(var + EPS);
    ab3[t] = al;
    ab3[64 + t] = be3[t] - mu * al;
  }
  __syncthreads();
  if (t >= N_GRAPHS) return;
  u32 cntn = bounds[t + 1] - bounds[t];
  float inv = (cntn > 0) ? 1.f / (float)cntn : 0.f;
  float lg[10];
#pragma unroll
  for (int j = 0; j < 10; ++j) lg[j] = bo[j];
  for (int c = 0; c < 64; ++c) {
    float p = (cntn > 0) ? (sums[t * 64 + c] * inv * ab3[c] + ab3[64 + c]) : 0.f;
#pragma unroll
    for (int j = 0; j < 10; ++j) lg[j] = fmaf(p, Wo[c * 10 + j], lg[j]);
  }
  float mx = lg[0];
#pragma unroll
  for (int j = 1; j < 10; ++j) mx = fmaxf(mx, lg[j]);
  float ssum = 0.f, ex[10];
#pragma unroll
  for (int j = 0; j < 10; ++j) { ex[j] = expf(lg[j] - mx); ssum += ex[j]; }
#pragma unroll
  for (int j = 0; j < 10; ++j) out[t * 10 + j] = ex[j] / ssum;
}

extern "C" void kernel_launch(void* const* d_in, const int* in_sizes, int n_in,
                              void* d_out, int out_size, void* d_ws, size_t ws_size,
                              hipStream_t stream) {
  const float* x    = (const float*)d_in[0];
  const int*   ei   = (const int*)d_in[1];
  const int*   batch= (const int*)d_in[2];
  const float* W1 = (const float*)d_in[3];  const float* b1 = (const float*)d_in[4];
  const float* W2 = (const float*)d_in[5];  const float* b2 = (const float*)d_in[6];
  const float* W3 = (const float*)d_in[7];  const float* b3 = (const float*)d_in[8];
  const float* g1 = (const float*)d_in[9];  const float* be1= (const float*)d_in[10];
  const float* g2 = (const float*)d_in[11]; const float* be2= (const float*)d_in[12];
  const float* g3 = (const float*)d_in[13]; const float* be3= (const float*)d_in[14];
  const float* Wo = (const float*)d_in[15]; const float* bo = (const float*)d_in[16];
  float* out = (float*)d_out;

  char* p = (char*)d_ws;
  auto alloc = [&](size_t bytes) { void* r = (void*)p; p += (bytes + 255) & ~(size_t)255; return r; };
  uint4* Wb     = (uint4*)alloc(3072 * sizeof(uint4));
  u32*   bounds = (u32*)alloc(65 * sizeof(u32));
  u32*   bcur   = (u32*)alloc(NBUCK * sizeof(u32));
  u32*   cnt    = (u32*)alloc((size_t)N_NODES * sizeof(u32));
  u32*   offs   = (u32*)alloc((size_t)N_NODES * sizeof(u32));
  // contiguous zero region: sums (4096f) + bnacc (3*32*128 = 12288f)
  float* sums   = (float*)alloc(4096 * sizeof(float));
  float* bnacc  = (float*)alloc(12288 * sizeof(float));
  u32*   esrc   = (u32*)alloc((size_t)NBUCK * BSTRIDE * sizeof(u32));
  u32*   pairs  = (u32*)alloc((size_t)NBUCK * BSTRIDE * sizeof(u32));
  ushort* ub    = (ushort*)alloc((size_t)N_NODES * 64 * sizeof(ushort));
  ushort* vb    = (ushort*)alloc((size_t)N_NODES * 64 * sizeof(ushort));
  ushort* hb    = (ushort*)alloc((size_t)N_NODES * 64 * sizeof(ushort));

  const int* src = ei;
  const int* dst = ei + N_EDGES;

  hipMemsetAsync(bcur, 0, NBUCK * sizeof(u32), stream);
  // bscat (196) + weight pack (12) + bounds (1) + zero accumulators (1)
  bscat_setup_k<<<BSCAT_GRID + 14, 256, 0, stream>>>(src, dst, bcur, pairs,
                                                     W1, W2, W3, Wb, batch, bounds,
                                                     (u32*)sums);

  // fscat2 || layer-1 GEMM
  fused_fg_k<<<NBUCK + GEMM_TILES, 256, 0, stream>>>(bcur, pairs, esrc, offs, cnt,
                                                     x, Wb, b1, ub, vb);
  segmax_k<<<SEG_NBLK, 256, 0, stream>>>(vb, offs, cnt, esrc, ub, hb, bnacc);

  // ---- layer 2 ----
  gemm_k<<<GEMM_TILES, 256, 0, stream>>>(hb, Wb + 1024, bnacc, g1, be1, b2, ub, vb);
  segmax_k<<<SEG_NBLK, 256, 0, stream>>>(vb, offs, cnt, esrc, ub, hb, bnacc + 4096);

  // ---- layer 3 ----
  gemm_k<<<GEMM_TILES, 256, 0, stream>>>(hb, Wb + 2048, bnacc + 4096, g2, be2, b3, ub, vb);
  segmax_k<<<SEG_NBLK, 256, 0, stream>>>(vb, offs, cnt, esrc, ub, hb, bnacc + 8192);

  // ---- pool + head ----
  pool_part_k<<<dim3(16, N_GRAPHS), 256, 0, stream>>>(hb, bounds, sums);
  head_k<<<1, 64, 0, stream>>>(sums, bounds, bnacc + 8192, g3, be3, Wo, bo, out);
}

// Round 13
// 202.892 us; speedup vs baseline: 1.8087x; 1.0129x over previous
//
#include <hip/hip_runtime.h>
#include <hip/hip_bf16.h>
#include <math.h>

#define N_NODES 100000
#define N_EDGES 1600000
#define N_GRAPHS 64
#define EPS 1e-5f
#define NBUCK 391       // ceil(N_NODES / 256)
#define BSTRIDE 6144    // fixed per-bucket region (mean 4096, sigma~64)
#define BSCAT_GRID 196  // ceil(N_EDGES / 8192)
#define SEG_NBLK 3125   // 3125 * 32 = 100000 node slots (exact)
#define GEMM_TILES 1563 // ceil(N_NODES / 64)

typedef unsigned int u32;
typedef __attribute__((ext_vector_type(8))) short short8;
typedef __attribute__((ext_vector_type(4))) float f32x4;

static __device__ __forceinline__ ushort f2bf(float f) {
  u32 x = __float_as_uint(f);
  u32 r = (x + 0x7fffu + ((x >> 16) & 1u)) >> 16;  // RNE; inputs finite
  return (ushort)r;
}
static __device__ __forceinline__ float bflo(u32 w) { return __uint_as_float(w << 16); }
static __device__ __forceinline__ float bfhi(u32 w) { return __uint_as_float(w & 0xffff0000u); }
static __device__ __forceinline__ void decode8(uint4 w, float* f) {
  f[0] = bflo(w.x); f[1] = bfhi(w.x); f[2] = bflo(w.y); f[3] = bfhi(w.y);
  f[4] = bflo(w.z); f[5] = bfhi(w.z); f[6] = bflo(w.w); f[7] = bfhi(w.w);
}

// ---------- tiny zero (replaces pathological hipMemsetAsync fill) ----------
__global__ void zero_k(u32* __restrict__ p, int n) {
  int i = blockIdx.x * 256 + threadIdx.x;
  if (i < n) p[i] = 0u;
}

// ---------- pass C + setup: blocks [0,196) scatter edges into fixed-stride
// bucket regions; [196,208) pack weights; 208 = bounds; 209 = zero accums.
// Wb[layer][kh(2)][ct(8)][lane(64)] = uint4 (8 bf16): lane l, elem j ->
//   Wc[kh*32 + (l>>4)*8 + j][ct*16 + (l&15)], Wc = [A-B | B] (64 x 128)
__global__ __launch_bounds__(256) void bscat_setup_k(
    const int* __restrict__ src, const int* __restrict__ dst,
    u32* __restrict__ bcur, u32* __restrict__ pairs,
    const float* __restrict__ W1, const float* __restrict__ W2,
    const float* __restrict__ W3, uint4* __restrict__ Wb,
    const int* __restrict__ batch, u32* __restrict__ bounds,
    u32* __restrict__ zbase) {
  __shared__ u32 cnt[NBUCK];
  __shared__ u32 base[NBUCK];
  int bid = blockIdx.x, t = threadIdx.x;
  if (bid < BSCAT_GRID) {
    for (int i = t; i < NBUCK; i += 256) cnt[i] = 0;
    __syncthreads();
    u32 pk[32], bk[32];
    int be = bid * 8192;
#pragma unroll
    for (int k = 0; k < 32; ++k) {
      int e = be + k * 256 + t;
      if (e < N_EDGES) {
        u32 d = (u32)dst[e], s = (u32)src[e];
        u32 b = d >> 8;
        pk[k] = ((d & 255u) << 24) | s;
        bk[k] = b;
        atomicAdd(&cnt[b], 1u);
      } else bk[k] = 0xFFFFFFFFu;
    }
    __syncthreads();
    for (int i = t; i < NBUCK; i += 256) {
      u32 c = cnt[i];
      base[i] = c ? (i * BSTRIDE + atomicAdd(&bcur[i], c)) : 0u;
      cnt[i] = 0;
    }
    __syncthreads();
#pragma unroll
    for (int k = 0; k < 32; ++k) {
      if (bk[k] != 0xFFFFFFFFu) {
        u32 p = base[bk[k]] + atomicAdd(&cnt[bk[k]], 1u);
        pairs[p] = pk[k];
      }
    }
  } else if (bid < BSCAT_GRID + 12) {
    int g = (bid - BSCAT_GRID) * 256 + t;
    if (g >= 3072) return;
    int layer = g >> 10, rem = g & 1023;
    int kh = rem >> 9, ct = (rem >> 6) & 7, l = rem & 63;
    const float* W = (layer == 0) ? W1 : (layer == 1) ? W2 : W3;
    int c = ct * 16 + (l & 15);
    u32 w[4];
#pragma unroll
    for (int jj = 0; jj < 4; ++jj) {
      int k0 = kh * 32 + (l >> 4) * 8 + 2 * jj;
      float v0, v1;
      if (c < 64) {
        v0 = W[k0 * 64 + c] - W[(64 + k0) * 64 + c];
        v1 = W[(k0 + 1) * 64 + c] - W[(65 + k0) * 64 + c];
      } else {
        v0 = W[(64 + k0) * 64 + (c - 64)];
        v1 = W[(65 + k0) * 64 + (c - 64)];
      }
      w[jj] = (u32)f2bf(v0) | ((u32)f2bf(v1) << 16);
    }
    Wb[g] = make_uint4(w[0], w[1], w[2], w[3]);
  } else if (bid == BSCAT_GRID + 12) {
    if (t > 64) return;
    int lo = 0, hi = N_NODES;
    while (lo < hi) {
      int mid = (lo + hi) >> 1;
      if (batch[mid] < t) lo = mid + 1; else hi = mid;
    }
    bounds[t] = (u32)lo;
  } else {
    // zero sums (4096) + bnacc (12288)
    for (int i = t; i < 16384; i += 256) zbase[i] = 0u;
  }
}

// ---------- fscat2 body: per-bucket node CSR (LDS hist+scan) + place ----------
static __device__ __forceinline__ void fscat2_body(
    int b, u32* SH, const u32* __restrict__ bcur, const u32* __restrict__ pairs,
    u32* __restrict__ esrc, u32* __restrict__ offs_g, u32* __restrict__ cnt_g) {
  u32* lcnt = SH; u32* lexc = SH + 256; u32* lcur = SH + 512;
  int t = threadIdx.x;
  u32 s0 = b * BSTRIDE, e0 = s0 + bcur[b];
  lcnt[t] = 0;
  __syncthreads();
  for (u32 p = s0 + t; p < e0; p += 256) atomicAdd(&lcnt[pairs[p] >> 24], 1u);
  __syncthreads();
  u32 v = lcnt[t];
  lexc[t] = v;
  __syncthreads();
  for (int d = 1; d < 256; d <<= 1) {
    u32 a = (t >= d) ? lexc[t - d] : 0u;
    __syncthreads();
    lexc[t] += a;
    __syncthreads();
  }
  u32 excl = lexc[t] - v;
  int node = (b << 8) + t;
  if (node < N_NODES) { offs_g[node] = s0 + excl; cnt_g[node] = v; }
  lcur[t] = 0;
  lexc[t] = excl;
  __syncthreads();
  for (u32 p = s0 + t; p < e0; p += 256) {
    u32 pk = pairs[p];
    u32 dl = pk >> 24;
    u32 l = atomicAdd(&lcur[dl], 1u);
    esrc[s0 + lexc[dl] + l] = pk & 0x00FFFFFFu;
  }
}

// ---------- MFMA GEMM body: [u | v] = act(X) @ [A-B | B], u/v bf16 out ----------
// One 64-row tile; 4 waves; Xl XOR-swizzled (byte^=(row&7)<<4).
static __device__ __forceinline__ void gemm_body(
    int tile, u32* Xl,
    const void* __restrict__ xin, int xbf16, const uint4* __restrict__ Wb,
    const float* ab, const float* __restrict__ bias,
    ushort* __restrict__ ub, ushort* __restrict__ vb) {
  int t = threadIdx.x;
  int l = t & 63, wv = t >> 6;
  short8 bs[2][8];
#pragma unroll
  for (int kh = 0; kh < 2; ++kh)
#pragma unroll
    for (int ct = 0; ct < 8; ++ct) {
      uint4 tmp = Wb[(kh * 8 + ct) * 64 + l];
      __builtin_memcpy(&bs[kh][ct], &tmp, 16);
    }
  int srow = t >> 2, scol = (t & 3) * 16;
  int rb = tile * 64;
  int gr = rb + srow;
  u32 xb[8];
  if (gr < N_NODES) {
    if (xbf16) {
      const uint4* xp = (const uint4*)((const ushort*)xin + (size_t)gr * 64 + scol);
      uint4 p0 = xp[0], p1 = xp[1];
      u32 raw[8] = {p0.x, p0.y, p0.z, p0.w, p1.x, p1.y, p1.z, p1.w};
#pragma unroll
      for (int q = 0; q < 8; ++q) {
        int c = scol + 2 * q;
        float lo = fmaxf(fmaf(bflo(raw[q]), ab[c], ab[64 + c]), 0.f);
        float hi = fmaxf(fmaf(bfhi(raw[q]), ab[c + 1], ab[64 + c + 1]), 0.f);
        xb[q] = (u32)f2bf(lo) | ((u32)f2bf(hi) << 16);
      }
    } else {
      const float4* xp = (const float4*)((const float*)xin + (size_t)gr * 64 + scol);
#pragma unroll
      for (int q = 0; q < 4; ++q) {
        float4 a = xp[q];
        xb[2 * q]     = (u32)f2bf(a.x) | ((u32)f2bf(a.y) << 16);
        xb[2 * q + 1] = (u32)f2bf(a.z) | ((u32)f2bf(a.w) << 16);
      }
    }
  } else {
#pragma unroll
    for (int q = 0; q < 8; ++q) xb[q] = 0u;
  }
  int byte0 = srow * 128 + ((scol * 2) ^ ((srow & 7) << 4));
  int byte1 = srow * 128 + ((scol * 2 + 16) ^ ((srow & 7) << 4));
  *(uint4*)((char*)Xl + byte0) = make_uint4(xb[0], xb[1], xb[2], xb[3]);
  *(uint4*)((char*)Xl + byte1) = make_uint4(xb[4], xb[5], xb[6], xb[7]);
  __syncthreads();
  f32x4 acc[8];
#pragma unroll
  for (int ct = 0; ct < 8; ++ct) {
    float b0 = (ct < 4) ? bias[ct * 16 + (l & 15)] : 0.f;
    acc[ct] = (f32x4){b0, b0, b0, b0};
  }
  int arow = wv * 16 + (l & 15);
#pragma unroll
  for (int kh = 0; kh < 2; ++kh) {
    int abyte = arow * 128 + ((kh * 64 + ((l >> 4) * 16)) ^ ((arow & 7) << 4));
    short8 af = *(const short8*)((const char*)Xl + abyte);
#pragma unroll
    for (int ct = 0; ct < 8; ++ct)
      acc[ct] = __builtin_amdgcn_mfma_f32_16x16x32_bf16(af, bs[kh][ct], acc[ct], 0, 0, 0);
  }
  // C layout: col = l&15, row = 4*(l>>4)+reg (m89-verified)
  int rloc = rb + wv * 16 + 4 * (l >> 4);
#pragma unroll
  for (int ct = 0; ct < 4; ++ct) {
    int col = ct * 16 + (l & 15);
#pragma unroll
    for (int r = 0; r < 4; ++r) {
      int row = rloc + r;
      if (row < N_NODES) ub[(size_t)row * 64 + col] = f2bf(acc[ct][r]);
    }
  }
#pragma unroll
  for (int ct = 4; ct < 8; ++ct) {
    int col = ct * 16 + (l & 15) - 64;
#pragma unroll
    for (int r = 0; r < 4; ++r) {
      int row = rloc + r;
      if (row < N_NODES) vb[(size_t)row * 64 + col] = f2bf(acc[ct][r]);
    }
  }
}

// ---------- fused: fscat2 (391 blocks) || layer-1 GEMM (1563 blocks) ----------
__global__ __launch_bounds__(256) void fused_fg_k(
    const u32* __restrict__ bcur, const u32* __restrict__ pairs,
    u32* __restrict__ esrc, u32* __restrict__ offs_g, u32* __restrict__ cnt_g,
    const float* __restrict__ x, const uint4* __restrict__ Wb,
    const float* __restrict__ bias, ushort* __restrict__ ub, ushort* __restrict__ vb) {
  __shared__ u32 SH[2048];  // 8KB
  int bid = blockIdx.x;
  if (bid < NBUCK) fscat2_body(bid, SH, bcur, pairs, esrc, offs_g, cnt_g);
  else gemm_body(bid - NBUCK, SH, x, 0, Wb, nullptr, bias, ub, vb);
}

// ---------- standalone GEMM (layers 2,3): BN affine computed from bnacc slices ----------
__global__ __launch_bounds__(256) void gemm_k(
    const ushort* __restrict__ xin, const uint4* __restrict__ Wb,
    const float* __restrict__ bnacc, const float* __restrict__ g,
    const float* __restrict__ be, const float* __restrict__ bias,
    ushort* __restrict__ ub, ushort* __restrict__ vb) {
  __shared__ u32 Xl[2048];
  __shared__ float ab_sh[128];
  int t = threadIdx.x;
  if (t < 64) {
    float s1 = 0.f, s2 = 0.f;
    for (int s = 0; s < 32; ++s) {
      s1 += bnacc[s * 128 + t];
      s2 += bnacc[s * 128 + 64 + t];
    }
    float mu = s1 / (float)N_NODES;
    float var = s2 / (float)N_NODES - mu * mu;
    float al = g[t] / sqrtf(var + EPS);
    ab_sh[t] = al;
    ab_sh[64 + t] = be[t] - mu * al;
  }
  __syncthreads();
  gemm_body(blockIdx.x, Xl, xin, 1, Wb, ab_sh, bias, ub, vb);
}

// ---------- segmax: 1 node/slot, 8 lanes/node, uint4 gathers, unroll-4 ----------
// h = relu(u + max); LAST=0: store bf16 h + BN partials.
// LAST=1: no h store; BN partials + fused per-graph pooling into sums.
template <int LAST>
__global__ __launch_bounds__(256) void segmax_k(
    const ushort* __restrict__ v, const u32* __restrict__ offs,
    const u32* __restrict__ cnt, const u32* __restrict__ esrc,
    const ushort* __restrict__ ub, ushort* __restrict__ hb,
    float* __restrict__ bnacc, const u32* __restrict__ bounds,
    float* __restrict__ sums) {
  __shared__ float red[2048];
  __shared__ u32 bsh[65];
  __shared__ int gmin_sh, mflag;
  int t = threadIdx.x;
  if (LAST) {
    if (t < 65) bsh[t] = bounds[t];
    if (t == 0) mflag = 0;
    __syncthreads();
  }
  int lane = t & 63;
  int op = lane & 7;        // uint4 index within row (8 channels)
  int sub = lane >> 3;      // node sub-group within wave
  int wv = t >> 6;
  int node = blockIdx.x * 32 + wv * 8 + sub;   // grid*32 == N_NODES exactly
  const uint4* v4 = (const uint4*)v;
  const uint4* u4 = (const uint4*)ub;
  u32 off = offs[node], deg = cnt[node];
  const u32* ep = esrc + off;
  float m[8];
#pragma unroll
  for (int j = 0; j < 8; ++j) m[j] = -INFINITY;
  u32 i = 0;
  for (; i + 4 <= deg; i += 4) {
    u32 sA = ep[i], sB = ep[i + 1], sC = ep[i + 2], sD = ep[i + 3];
    uint4 wA = v4[(size_t)sA * 8 + op];
    uint4 wB = v4[(size_t)sB * 8 + op];
    uint4 wC = v4[(size_t)sC * 8 + op];
    uint4 wD = v4[(size_t)sD * 8 + op];
    float fA[8], fB[8], fC[8], fD[8];
    decode8(wA, fA); decode8(wB, fB); decode8(wC, fC); decode8(wD, fD);
#pragma unroll
    for (int j = 0; j < 8; ++j)
      m[j] = fmaxf(fmaxf(m[j], fmaxf(fA[j], fB[j])), fmaxf(fC[j], fD[j]));
  }
  for (; i < deg; ++i) {
    uint4 w = v4[(size_t)ep[i] * 8 + op];
    float f[8]; decode8(w, f);
#pragma unroll
    for (int j = 0; j < 8; ++j) m[j] = fmaxf(m[j], f[j]);
  }
  uint4 uu = u4[(size_t)node * 8 + op];
  float uf[8]; decode8(uu, uf);
  float h[8];
#pragma unroll
  for (int j = 0; j < 8; ++j) h[j] = fmaxf(uf[j] + m[j], 0.f);  // relu(-inf)=0
  int g = 0;
  if (LAST) {
    // graph of this node: upper bound over bsh
    int lo = 0, hi = N_GRAPHS - 1;
    while (lo < hi) {
      int mid = (lo + hi + 1) >> 1;
      if (bsh[mid] <= (u32)node) lo = mid; else hi = mid - 1;
    }
    g = lo;
    if (t == 0) gmin_sh = g;
  } else {
    uint4 hw;
    hw.x = (u32)f2bf(h[0]) | ((u32)f2bf(h[1]) << 16);
    hw.y = (u32)f2bf(h[2]) | ((u32)f2bf(h[3]) << 16);
    hw.z = (u32)f2bf(h[4]) | ((u32)f2bf(h[5]) << 16);
    hw.w = (u32)f2bf(h[6]) | ((u32)f2bf(h[7]) << 16);
    ((uint4*)hb)[(size_t)node * 8 + op] = hw;
  }
  // BN partials: channel c = op*8 + j; reduce 32 nodes per block
#pragma unroll
  for (int j = 0; j < 8; ++j) red[t * 8 + j] = h[j];
  __syncthreads();
  float o1 = 0.f, o2 = 0.f;
  int cop = t >> 3, cj = t & 7;
  if (t < 64) {
    for (int q = 0; q < 32; ++q) o1 += red[(q * 8 + cop) * 8 + cj];
  }
  __syncthreads();
#pragma unroll
  for (int j = 0; j < 8; ++j) red[t * 8 + j] = h[j] * h[j];
  __syncthreads();
  if (t < 64) {
    for (int q = 0; q < 32; ++q) o2 += red[(q * 8 + cop) * 8 + cj];
    int slice = blockIdx.x & 31;
    atomicAdd(&bnacc[slice * 128 + t], o1);
    atomicAdd(&bnacc[slice * 128 + 64 + t], o2);
  }
  if (LAST) {
    __syncthreads();
    int gmin = gmin_sh;
    int slot = g - gmin;
    // pool pass A (graph gmin)
#pragma unroll
    for (int j = 0; j < 8; ++j) red[t * 8 + j] = (slot == 0) ? h[j] : 0.f;
    if (slot != 0) mflag = 1;  // benign race
    __syncthreads();
    if (t < 64) {
      float o = 0.f;
      for (int q = 0; q < 32; ++q) o += red[(q * 8 + cop) * 8 + cj];
      atomicAdd(&sums[gmin * 64 + t], o);
    }
    if (mflag) {  // uniform (LDS) branch
      __syncthreads();
#pragma unroll
      for (int j = 0; j < 8; ++j) red[t * 8 + j] = (slot == 1) ? h[j] : 0.f;
      __syncthreads();
      if (t < 64) {
        float o = 0.f;
        for (int q = 0; q < 32; ++q) o += red[(q * 8 + cop) * 8 + cj];
        atomicAdd(&sums[(gmin + 1) * 64 + t], o);
      }
      if (slot >= 2) {  // astronomically rare; correct fallback
#pragma unroll
        for (int j = 0; j < 8; ++j) atomicAdd(&sums[g * 64 + op * 8 + j], h[j]);
      }
    }
  }
}

// ---------- head: BN3 affine + mean + linear + softmax (1 block) ----------
__global__ void head_k(const float* __restrict__ sums, const u32* __restrict__ bounds,
                       const float* __restrict__ bnacc3, const float* __restrict__ g3,
                       const float* __restrict__ be3, const float* __restrict__ Wo,
                       const float* __restrict__ bo, float* __restrict__ out) {
  __shared__ float ab3[128];
  int t = threadIdx.x;
  if (t < 64) {
    float s1 = 0.f, s2 = 0.f;
    for (int sl = 0; sl < 32; ++sl) {
      s1 += bnacc3[sl * 128 + t];
      s2 += bnacc3[sl * 128 + 64 + t];
    }
    float mu = s1 / (float)N_NODES;
    float var = s2 / (float)N_NODES - mu * mu;
    float al = g3[t] / sqrtf(var + EPS);
    ab3[t] = al;
    ab3[64 + t] = be3[t] - mu * al;
  }
  __syncthreads();
  if (t >= N_GRAPHS) return;
  u32 cntn = bounds[t + 1] - bounds[t];
  float inv = (cntn > 0) ? 1.f / (float)cntn : 0.f;
  float lg[10];
#pragma unroll
  for (int j = 0; j < 10; ++j) lg[j] = bo[j];
  for (int c = 0; c < 64; ++c) {
    float p = (cntn > 0) ? (sums[t * 64 + c] * inv * ab3[c] + ab3[64 + c]) : 0.f;
#pragma unroll
    for (int j = 0; j < 10; ++j) lg[j] = fmaf(p, Wo[c * 10 + j], lg[j]);
  }
  float mx = lg[0];
#pragma unroll
  for (int j = 1; j < 10; ++j) mx = fmaxf(mx, lg[j]);
  float ssum = 0.f, ex[10];
#pragma unroll
  for (int j = 0; j < 10; ++j) { ex[j] = expf(lg[j] - mx); ssum += ex[j]; }
#pragma unroll
  for (int j = 0; j < 10; ++j) out[t * 10 + j] = ex[j] / ssum;
}

extern "C" void kernel_launch(void* const* d_in, const int* in_sizes, int n_in,
                              void* d_out, int out_size, void* d_ws, size_t ws_size,
                              hipStream_t stream) {
  const float* x    = (const float*)d_in[0];
  const int*   ei   = (const int*)d_in[1];
  const int*   batch= (const int*)d_in[2];
  const float* W1 = (const float*)d_in[3];  const float* b1 = (const float*)d_in[4];
  const float* W2 = (const float*)d_in[5];  const float* b2 = (const float*)d_in[6];
  const float* W3 = (const float*)d_in[7];  const float* b3 = (const float*)d_in[8];
  const float* g1 = (const float*)d_in[9];  const float* be1= (const float*)d_in[10];
  const float* g2 = (const float*)d_in[11]; const float* be2= (const float*)d_in[12];
  const float* g3 = (const float*)d_in[13]; const float* be3= (const float*)d_in[14];
  const float* Wo = (const float*)d_in[15]; const float* bo = (const float*)d_in[16];
  float* out = (float*)d_out;

  char* p = (char*)d_ws;
  auto alloc = [&](size_t bytes) { void* r = (void*)p; p += (bytes + 255) & ~(size_t)255; return r; };
  uint4* Wb     = (uint4*)alloc(3072 * sizeof(uint4));
  u32*   bounds = (u32*)alloc(65 * sizeof(u32));
  u32*   bcur   = (u32*)alloc(NBUCK * sizeof(u32));
  u32*   cnt    = (u32*)alloc((size_t)N_NODES * sizeof(u32));
  u32*   offs   = (u32*)alloc((size_t)N_NODES * sizeof(u32));
  // contiguous zero region: sums (4096f) + bnacc (3*32*128 = 12288f)
  float* sums   = (float*)alloc(4096 * sizeof(float));
  float* bnacc  = (float*)alloc(12288 * sizeof(float));
  u32*   esrc   = (u32*)alloc((size_t)NBUCK * BSTRIDE * sizeof(u32));
  u32*   pairs  = (u32*)alloc((size_t)NBUCK * BSTRIDE * sizeof(u32));
  ushort* ub    = (ushort*)alloc((size_t)N_NODES * 64 * sizeof(ushort));
  ushort* vb    = (ushort*)alloc((size_t)N_NODES * 64 * sizeof(ushort));
  ushort* hb    = (ushort*)alloc((size_t)N_NODES * 64 * sizeof(ushort));

  const int* src = ei;
  const int* dst = ei + N_EDGES;

  zero_k<<<2, 256, 0, stream>>>(bcur, NBUCK);
  // bscat (196) + weight pack (12) + bounds (1) + zero accumulators (1)
  bscat_setup_k<<<BSCAT_GRID + 14, 256, 0, stream>>>(src, dst, bcur, pairs,
                                                     W1, W2, W3, Wb, batch, bounds,
                                                     (u32*)sums);

  // fscat2 || layer-1 GEMM
  fused_fg_k<<<NBUCK + GEMM_TILES, 256, 0, stream>>>(bcur, pairs, esrc, offs, cnt,
                                                     x, Wb, b1, ub, vb);
  segmax_k<0><<<SEG_NBLK, 256, 0, stream>>>(vb, offs, cnt, esrc, ub, hb, bnacc,
                                            bounds, sums);

  // ---- layer 2 ----
  gemm_k<<<GEMM_TILES, 256, 0, stream>>>(hb, Wb + 1024, bnacc, g1, be1, b2, ub, vb);
  segmax_k<0><<<SEG_NBLK, 256, 0, stream>>>(vb, offs, cnt, esrc, ub, hb, bnacc + 4096,
                                            bounds, sums);

  // ---- layer 3 (pool fused into segmax) ----
  gemm_k<<<GEMM_TILES, 256, 0, stream>>>(hb, Wb + 2048, bnacc + 4096, g2, be2, b3, ub, vb);
  segmax_k<1><<<SEG_NBLK, 256, 0, stream>>>(vb, offs, cnt, esrc, ub, hb, bnacc + 8192,
                                            bounds, sums);

  // ---- head ----
  head_k<<<1, 64, 0, stream>>>(sums, bounds, bnacc + 8192, g3, be3, Wo, bo, out);
}